// Round 17
// baseline (120.510 us; speedup 1.0000x reference)
//
#include <hip/hip_runtime.h>
#include <hip/hip_bf16.h>

#define NFEAT 1024
#define NHEAD 16
#define DK 64
#define TCHUNK 1024
#define MAXTOK 4096
#define NSPLIT 4

using bf16x8 = __attribute__((ext_vector_type(8))) short;
using f32x4  = __attribute__((ext_vector_type(4))) float;
using f32x16 = __attribute__((ext_vector_type(16))) float;
using u32x4  = __attribute__((ext_vector_type(4))) unsigned int;

__device__ __forceinline__ short f2bf(float f) {
    __hip_bfloat16 h = __float2bfloat16(f);
    return *reinterpret_cast<short*>(&h);
}

__device__ __forceinline__ float exp2fast(float x) {
    return __builtin_amdgcn_exp2f(x);
}

__device__ __forceinline__ unsigned int pack2bf(float a, float b) {
    unsigned int lo = (unsigned int)(unsigned short)f2bf(a);
    unsigned int hi = (unsigned int)(unsigned short)f2bf(b);
    return lo | (hi << 16);
}

// log2(e)/sqrt(DK): folds the 1/sqrt(64) and the exp->exp2 conversion
#define QSCALE 0.1803368801f

// ---------------------------------------------------------------------------
// pack: blocks [0,1024): transpose+convert W{q,k,v,o} -> Wt[4096 n][1024 k]
//       blocks [1024,1792): gather cache tokens -> kg[h][tok][d], vt[h][d][tok]
// (x is consumed directly as f32 by qkv_gemm — no xb intermediate.)
// ---------------------------------------------------------------------------
__global__ __launch_bounds__(256) void pack_kernel(
    const float* __restrict__ Wq, const float* __restrict__ Wk,
    const float* __restrict__ Wv, const float* __restrict__ Wo,
    const float* __restrict__ kc, const float* __restrict__ vc,
    const int* __restrict__ btab, const int* __restrict__ soff,
    short* __restrict__ Wt, short* __restrict__ kg, short* __restrict__ vt) {
    const int b = blockIdx.x;
    const int t = threadIdx.x;
    if (b < 1024) {
        __shared__ short T[64][72];
        const int w = b >> 8, tile = b & 255;
        const int k0 = (tile >> 4) << 6, n0 = (tile & 15) << 6;
        const float* W = (w == 0) ? Wq : (w == 1) ? Wk : (w == 2) ? Wv : Wo;
        const int r = t >> 2, cs = (t & 3) << 4;
        #pragma unroll
        for (int u = 0; u < 4; ++u) {
            float4 v = *reinterpret_cast<const float4*>(
                &W[(size_t)(k0 + r) * NFEAT + n0 + cs + u * 4]);
            T[cs + u * 4 + 0][r] = f2bf(v.x);
            T[cs + u * 4 + 1][r] = f2bf(v.y);
            T[cs + u * 4 + 2][r] = f2bf(v.z);
            T[cs + u * 4 + 3][r] = f2bf(v.w);
        }
        __syncthreads();
        const int c = t >> 2, rs = (t & 3) << 4;
        bf16x8 a0 = *reinterpret_cast<const bf16x8*>(&T[c][rs]);
        bf16x8 a1 = *reinterpret_cast<const bf16x8*>(&T[c][rs + 8]);
        size_t drow = (size_t)(w * 1024 + n0 + c) * NFEAT + k0 + rs;
        *reinterpret_cast<bf16x8*>(&Wt[drow]) = a0;
        *reinterpret_cast<bf16x8*>(&Wt[drow + 8]) = a1;
    } else {
        // cache-token gather (tokens [0, offset))
        __shared__ short TV[64][72];
        const int cb = b - 1024;
        const int h = cb & 15;
        const int t0 = (cb >> 4) << 6;
        const int offset = soff[0];
        const int row = t >> 2, ds = (t & 3) << 4;
        const int tok = t0 + row;
        short kv[16], vv[16];
        if (tok < offset) {
            int phys = btab[tok >> 5];
            size_t base = ((size_t)(phys * 32 + (tok & 31)) * NHEAD + h) * DK + ds;
            #pragma unroll
            for (int u = 0; u < 4; ++u) {
                float4 kf = *reinterpret_cast<const float4*>(&kc[base + u * 4]);
                float4 vf = *reinterpret_cast<const float4*>(&vc[base + u * 4]);
                kv[u * 4 + 0] = f2bf(kf.x); kv[u * 4 + 1] = f2bf(kf.y);
                kv[u * 4 + 2] = f2bf(kf.z); kv[u * 4 + 3] = f2bf(kf.w);
                vv[u * 4 + 0] = f2bf(vf.x); vv[u * 4 + 1] = f2bf(vf.y);
                vv[u * 4 + 2] = f2bf(vf.z); vv[u * 4 + 3] = f2bf(vf.w);
            }
        } else {
            #pragma unroll
            for (int e = 0; e < 16; ++e) { kv[e] = 0; vv[e] = 0; }
        }
        {
            bf16x8 a, bb;
            #pragma unroll
            for (int e = 0; e < 8; ++e) { a[e] = kv[e]; bb[e] = kv[8 + e]; }
            size_t kb = ((size_t)h * MAXTOK + tok) * DK + ds;
            *reinterpret_cast<bf16x8*>(&kg[kb]) = a;
            *reinterpret_cast<bf16x8*>(&kg[kb + 8]) = bb;
        }
        #pragma unroll
        for (int e = 0; e < 16; ++e) TV[ds + e][row] = vv[e];
        __syncthreads();
        {
            const int d = t >> 2, ts = (t & 3) << 4;
            bf16x8 a = *reinterpret_cast<const bf16x8*>(&TV[d][ts]);
            bf16x8 bb = *reinterpret_cast<const bf16x8*>(&TV[d][ts + 8]);
            size_t vb = ((size_t)h * DK + d) * MAXTOK + t0 + ts;
            *reinterpret_cast<bf16x8*>(&vt[vb]) = a;
            *reinterpret_cast<bf16x8*>(&vt[vb + 8]) = bb;
        }
    }
}

// ---------------------------------------------------------------------------
// QKV MFMA GEMM (64x128 tile, 384 blocks). A staged directly from f32 x with
// inline bf16 convert. sel==0 -> qbuf (scaled); sel==1 -> kg; sel==2 -> vt.
// ---------------------------------------------------------------------------
__global__ __launch_bounds__(256) void qkv_gemm(
    const float* __restrict__ x, const short* __restrict__ Wt,
    const float* __restrict__ bq, const float* __restrict__ bk,
    const float* __restrict__ bv, const int* __restrict__ soff,
    short* __restrict__ qbuf, short* __restrict__ kg, short* __restrict__ vt) {
    __shared__ short As[64][72];
    __shared__ short Bs[128][72];
    const int tid = threadIdx.x;
    const int lane = tid & 63;
    const int w = tid >> 6;
    const int l15 = lane & 15, lg = lane >> 4;
    const int wr = w >> 1, wc = w & 1;
    const int m0 = blockIdx.y << 6, n0 = blockIdx.x << 7;
    const int sel = n0 >> 10;
    const float* bias = (sel == 0) ? bq : (sel == 1) ? bk : bv;

    f32x4 acc[2][4];
    #pragma unroll
    for (int i = 0; i < 2; ++i)
        #pragma unroll
        for (int j = 0; j < 4; ++j) acc[i][j] = (f32x4){0.f, 0.f, 0.f, 0.f};

    for (int k0 = 0; k0 < NFEAT; k0 += 64) {
        #pragma unroll
        for (int r = 0; r < 2; ++r) {
            int f = tid + (r << 8);
            int row = f >> 3, kc = (f & 7) << 3;
            float4 v0 = *reinterpret_cast<const float4*>(
                &x[(size_t)(m0 + row) * NFEAT + k0 + kc]);
            float4 v1 = *reinterpret_cast<const float4*>(
                &x[(size_t)(m0 + row) * NFEAT + k0 + kc + 4]);
            bf16x8 o;
            o[0] = f2bf(v0.x); o[1] = f2bf(v0.y); o[2] = f2bf(v0.z); o[3] = f2bf(v0.w);
            o[4] = f2bf(v1.x); o[5] = f2bf(v1.y); o[6] = f2bf(v1.z); o[7] = f2bf(v1.w);
            *reinterpret_cast<bf16x8*>(&As[row][kc]) = o;
        }
        #pragma unroll
        for (int r = 0; r < 4; ++r) {
            int f = tid + (r << 8);
            int row = f >> 3, kc = (f & 7) << 3;
            *reinterpret_cast<bf16x8*>(&Bs[row][kc]) =
                *reinterpret_cast<const bf16x8*>(&Wt[(size_t)(n0 + row) * NFEAT + k0 + kc]);
        }
        __syncthreads();
        #pragma unroll
        for (int kk = 0; kk < 2; ++kk) {
            bf16x8 am[2], bn[4];
            #pragma unroll
            for (int mi = 0; mi < 2; ++mi)
                am[mi] = *reinterpret_cast<const bf16x8*>(
                    &As[wr * 32 + mi * 16 + l15][kk * 32 + lg * 8]);
            #pragma unroll
            for (int ni = 0; ni < 4; ++ni)
                bn[ni] = *reinterpret_cast<const bf16x8*>(
                    &Bs[wc * 64 + ni * 16 + l15][kk * 32 + lg * 8]);
            #pragma unroll
            for (int mi = 0; mi < 2; ++mi)
                #pragma unroll
                for (int ni = 0; ni < 4; ++ni)
                    acc[mi][ni] = __builtin_amdgcn_mfma_f32_16x16x32_bf16(
                        am[mi], bn[ni], acc[mi][ni], 0, 0, 0);
        }
        __syncthreads();
    }
    const int offs = soff[0];
    #pragma unroll
    for (int mi = 0; mi < 2; ++mi)
        #pragma unroll
        for (int rr = 0; rr < 4; ++rr) {
            int m = m0 + wr * 32 + mi * 16 + lg * 4 + rr;
            #pragma unroll
            for (int ni = 0; ni < 4; ++ni) {
                int n = n0 + wc * 64 + ni * 16 + l15;
                float v = acc[mi][ni][rr] + bias[n & 1023];
                if (sel == 0) {
                    qbuf[(size_t)m * NFEAT + n] = f2bf(v * QSCALE);
                } else if (sel == 1) {
                    int nn = n - 1024, hh = nn >> 6, dd = nn & 63;
                    kg[((size_t)hh * MAXTOK + offs + m) * DK + dd] = f2bf(v);
                } else {
                    int nn = n - 2048, hh = nn >> 6, dd = nn & 63;
                    vt[((size_t)hh * DK + dd) * MAXTOK + offs + m] = f2bf(v);
                }
            }
        }
}

// ---------------------------------------------------------------------------
// Output MFMA GEMM: out[1024][1024] f32 = ctxb @ Wo + bo.
// ---------------------------------------------------------------------------
__global__ __launch_bounds__(256) void out_gemm(
    const short* __restrict__ ctxb, const short* __restrict__ Wt,
    const float* __restrict__ bo, float* __restrict__ out) {
    __shared__ short As[64][72];
    __shared__ short Bs[64][72];
    const int tid = threadIdx.x;
    const int lane = tid & 63;
    const int w = tid >> 6;
    const int l15 = lane & 15, lg = lane >> 4;
    const int wr = w >> 1, wc = w & 1;
    const int m0 = blockIdx.y << 6, n0 = blockIdx.x << 6;

    f32x4 acc[2][2];
    #pragma unroll
    for (int i = 0; i < 2; ++i)
        #pragma unroll
        for (int j = 0; j < 2; ++j) acc[i][j] = (f32x4){0.f, 0.f, 0.f, 0.f};

    for (int k0 = 0; k0 < NFEAT; k0 += 64) {
        #pragma unroll
        for (int r = 0; r < 2; ++r) {
            int f = tid + (r << 8);
            int row = f >> 3, kc = (f & 7) << 3;
            *reinterpret_cast<bf16x8*>(&As[row][kc]) =
                *reinterpret_cast<const bf16x8*>(&ctxb[(size_t)(m0 + row) * NFEAT + k0 + kc]);
            *reinterpret_cast<bf16x8*>(&Bs[row][kc]) =
                *reinterpret_cast<const bf16x8*>(
                    &Wt[(size_t)(3072 + n0 + row) * NFEAT + k0 + kc]);
        }
        __syncthreads();
        #pragma unroll
        for (int kk = 0; kk < 2; ++kk) {
            bf16x8 am[2], bn[2];
            #pragma unroll
            for (int mi = 0; mi < 2; ++mi)
                am[mi] = *reinterpret_cast<const bf16x8*>(
                    &As[wr * 32 + mi * 16 + l15][kk * 32 + lg * 8]);
            #pragma unroll
            for (int ni = 0; ni < 2; ++ni)
                bn[ni] = *reinterpret_cast<const bf16x8*>(
                    &Bs[wc * 32 + ni * 16 + l15][kk * 32 + lg * 8]);
            #pragma unroll
            for (int mi = 0; mi < 2; ++mi)
                #pragma unroll
                for (int ni = 0; ni < 2; ++ni)
                    acc[mi][ni] = __builtin_amdgcn_mfma_f32_16x16x32_bf16(
                        am[mi], bn[ni], acc[mi][ni], 0, 0, 0);
        }
        __syncthreads();
    }
    #pragma unroll
    for (int mi = 0; mi < 2; ++mi)
        #pragma unroll
        for (int rr = 0; rr < 4; ++rr) {
            int m = m0 + wr * 32 + mi * 16 + lg * 4 + rr;
            #pragma unroll
            for (int ni = 0; ni < 2; ++ni) {
                int n = n0 + wc * 32 + ni * 16 + l15;
                out[(size_t)m * NFEAT + n] = acc[mi][ni][rr] + bo[n];
            }
        }
}

// ---------------------------------------------------------------------------
// MFMA flash attention v16 — swapped-operand 32x32, P fully in-register.
// Grid (16 h, 16 qt, 4 z), block 128 (2 waves), each wave 32 q-rows.
// ---------------------------------------------------------------------------
__global__ __launch_bounds__(128, 2) void attn_mfma(
    const short* __restrict__ qbuf, const short* __restrict__ kg,
    const short* __restrict__ vt, const int* __restrict__ soff,
    float* __restrict__ pacc) {
    __shared__ short Ks[64][72];
    __shared__ short Vs[64][72];   // [d][tok]

    const int tid = threadIdx.x;
    const int lane = tid & 63;
    const int w = tid >> 6;        // 0/1
    const int l31 = lane & 31;
    const int hi = lane >> 5;
    const int h = blockIdx.x;
    const int qt = blockIdx.y;
    const int z = blockIdx.z;
    const int offset = soff[0];
    const int total = offset + TCHUNK;
    const int ntiles = (total + 63) >> 6;
    const int NT = (ntiles + NSPLIT - 1) / NSPLIT;
    const int tbase = z * NT;
    const int tend = min(tbase + NT, ntiles);

    const int srow = tid >> 1;           // 0..63 (tok for K, d for V)
    const int sseg = (tid & 1) << 5;     // 0 or 32

    const short* kbase = kg + (size_t)h * MAXTOK * DK;
    const short* vbase = vt + (size_t)h * DK * MAXTOK;

    // Q B-fragments: q = qt*64 + w*32 + l31, d = 16j + 8hi + e
    bf16x8 qf[4];
    {
        size_t qrow = (size_t)(qt * 64 + w * 32 + l31) * NFEAT + h * DK;
        #pragma unroll
        for (int j = 0; j < 4; ++j)
            qf[j] = *reinterpret_cast<const bf16x8*>(&qbuf[qrow + j * 16 + hi * 8]);
    }

    float m = -1e30f, lsum = 0.f;
    f32x16 accA, accB;
    #pragma unroll
    for (int i = 0; i < 16; ++i) { accA[i] = 0.f; accB[i] = 0.f; }

    bf16x8 kr[4], vr[4];
    if (tbase < tend) {
        int tok0 = tbase << 6;
        #pragma unroll
        for (int j = 0; j < 4; ++j) {
            kr[j] = *reinterpret_cast<const bf16x8*>(
                &kbase[(size_t)(tok0 + srow) * DK + sseg + j * 8]);
            vr[j] = *reinterpret_cast<const bf16x8*>(
                &vbase[(size_t)srow * MAXTOK + tok0 + sseg + j * 8]);
        }
    }

    for (int t = tbase; t < tend; ++t) {
        __syncthreads();   // previous tile fully consumed
        #pragma unroll
        for (int j = 0; j < 4; ++j) {
            *reinterpret_cast<bf16x8*>(&Ks[srow][sseg + j * 8]) = kr[j];
            *reinterpret_cast<bf16x8*>(&Vs[srow][sseg + j * 8]) = vr[j];
        }
        __syncthreads();   // staged tile visible
        if (t + 1 < tend) {   // prefetch next tile into regs
            int tok0 = (t + 1) << 6;
            #pragma unroll
            for (int j = 0; j < 4; ++j) {
                kr[j] = *reinterpret_cast<const bf16x8*>(
                    &kbase[(size_t)(tok0 + srow) * DK + sseg + j * 8]);
                vr[j] = *reinterpret_cast<const bf16x8*>(
                    &vbase[(size_t)srow * MAXTOK + tok0 + sseg + j * 8]);
            }
        }

        const int kt0 = t << 6;
        // ---- S^T = K * Q^T (two tok-halves, 4 d-steps) ----
        f32x16 st0, st1;
        #pragma unroll
        for (int i = 0; i < 16; ++i) { st0[i] = 0.f; st1[i] = 0.f; }
        __builtin_amdgcn_s_setprio(1);
        #pragma unroll
        for (int j = 0; j < 4; ++j) {
            bf16x8 ka0 = *reinterpret_cast<const bf16x8*>(&Ks[l31][j * 16 + hi * 8]);
            bf16x8 ka1 = *reinterpret_cast<const bf16x8*>(&Ks[32 + l31][j * 16 + hi * 8]);
            st0 = __builtin_amdgcn_mfma_f32_32x32x16_bf16(ka0, qf[j], st0, 0, 0, 0);
            st1 = __builtin_amdgcn_mfma_f32_32x32x16_bf16(ka1, qf[j], st1, 0, 0, 0);
        }
        __builtin_amdgcn_s_setprio(0);
        // ---- mask (uniform last-tile branch) ----
        if (kt0 + 64 > total) {
            #pragma unroll
            for (int r = 0; r < 16; ++r) {
                int crow = (r & 3) + 8 * (r >> 2) + 4 * hi;
                if (kt0 + crow >= total) st0[r] = -1e30f;
                if (kt0 + 32 + crow >= total) st1[r] = -1e30f;
            }
        }
        // ---- in-lane row max + cross-half ----
        float lm = st0[0];
        #pragma unroll
        for (int r = 1; r < 16; ++r) lm = fmaxf(lm, st0[r]);
        #pragma unroll
        for (int r = 0; r < 16; ++r) lm = fmaxf(lm, st1[r]);
        float full = fmaxf(lm, __shfl_xor(lm, 32));
        // ---- defer-max ----
        if (!__all(full <= m + 8.f)) {
            float mn = fmaxf(m, full);
            float sc = exp2fast(m - mn);
            m = mn;
            lsum *= sc;
            #pragma unroll
            for (int r = 0; r < 16; ++r) {
                int crow = (r & 3) + 8 * (r >> 2) + 4 * hi;
                float scr = __shfl(sc, crow);
                accA[r] *= scr;
                accB[r] *= scr;
            }
        }
        // ---- P = exp2(s - m), pack to bf16 pairs, accumulate row-sum ----
        unsigned int pk0[8], pk1[8];
        #pragma unroll
        for (int c = 0; c < 8; ++c) {
            float a0 = exp2fast(st0[2 * c] - m);
            float a1 = exp2fast(st0[2 * c + 1] - m);
            float b0 = exp2fast(st1[2 * c] - m);
            float b1 = exp2fast(st1[2 * c + 1] - m);
            lsum += (a0 + a1) + (b0 + b1);
            pk0[c] = pack2bf(a0, a1);
            pk1[c] = pack2bf(b0, b1);
        }
        // ---- PV: build PA per 16-k slot via cross-half exchange ----
        #pragma unroll
        for (int ks = 0; ks < 4; ++ks) {
            const int b4 = (ks & 1) * 4;
            unsigned int w0, w1, w2, w3;
            if (ks < 2) { w0 = pk0[b4]; w1 = pk0[b4 + 1]; w2 = pk0[b4 + 2]; w3 = pk0[b4 + 3]; }
            else        { w0 = pk1[b4]; w1 = pk1[b4 + 1]; w2 = pk1[b4 + 2]; w3 = pk1[b4 + 3]; }
            unsigned int x0 = __shfl_xor(hi ? w0 : w2, 32);
            unsigned int x1 = __shfl_xor(hi ? w1 : w3, 32);
            u32x4 uu;
            uu[0] = hi ? x0 : w0;
            uu[1] = hi ? x1 : w1;
            uu[2] = hi ? w2 : x0;
            uu[3] = hi ? w3 : x1;
            bf16x8 pa = __builtin_bit_cast(bf16x8, uu);
            bf16x8 bv0 = *reinterpret_cast<const bf16x8*>(&Vs[l31][ks * 16 + hi * 8]);
            bf16x8 bv1 = *reinterpret_cast<const bf16x8*>(&Vs[32 + l31][ks * 16 + hi * 8]);
            __builtin_amdgcn_s_setprio(1);
            accA = __builtin_amdgcn_mfma_f32_32x32x16_bf16(pa, bv0, accA, 0, 0, 0);
            accB = __builtin_amdgcn_mfma_f32_32x32x16_bf16(pa, bv1, accB, 0, 0, 0);
            __builtin_amdgcn_s_setprio(0);
        }
    }

    // ---- epilogue: combine halves' row-sum, write partials ----
    float lt = lsum + __shfl_xor(lsum, 32);
    const size_t pbase = (((size_t)z * NHEAD + h) * 16 + qt) * 4224;
    if (hi == 0) {
        int q = w * 32 + l31;
        pacc[pbase + 4096 + q] = m;
        pacc[pbase + 4160 + q] = lt;
    }
    #pragma unroll
    for (int r = 0; r < 16; ++r) {
        int crow = (r & 3) + 8 * (r >> 2) + 4 * hi;
        int q = w * 32 + crow;
        pacc[pbase + q * 64 + l31] = accA[r];
        pacc[pbase + q * 64 + 32 + l31] = accB[r];
    }
}

// ---------------------------------------------------------------------------
// merge NSPLIT split partials -> ctxb bf16 [1024 t][1024 (h*64+d)]
// ---------------------------------------------------------------------------
__global__ __launch_bounds__(256) void merge_ctx(
    const float* __restrict__ pacc, short* __restrict__ ctxb) {
    const int h = blockIdx.x, qt = blockIdx.y;
    const int t = threadIdx.x;
    const int q = t >> 2, ds = (t & 3) << 4;
    size_t b[NSPLIT];
    float mz[NSPLIT], lz[NSPLIT];
    float M = -1e30f;
    #pragma unroll
    for (int z = 0; z < NSPLIT; ++z) {
        b[z] = (((size_t)z * NHEAD + h) * 16 + qt) * 4224;
        mz[z] = pacc[b[z] + 4096 + q];
        lz[z] = pacc[b[z] + 4160 + q];
        M = fmaxf(M, mz[z]);
    }
    float L = 0.f, ez[NSPLIT];
    #pragma unroll
    for (int z = 0; z < NSPLIT; ++z) {
        ez[z] = __builtin_amdgcn_exp2f(mz[z] - M);
        L += lz[z] * ez[z];
    }
    float inv = 1.f / L;
    bf16x8 o0, o1;
    #pragma unroll
    for (int j = 0; j < 8; ++j) {
        float v = 0.f;
        #pragma unroll
        for (int z = 0; z < NSPLIT; ++z)
            v += pacc[b[z] + q * 64 + ds + j] * ez[z];
        o0[j] = f2bf(v * inv);
    }
    #pragma unroll
    for (int j = 0; j < 8; ++j) {
        float v = 0.f;
        #pragma unroll
        for (int z = 0; z < NSPLIT; ++z)
            v += pacc[b[z] + q * 64 + ds + 8 + j] * ez[z];
        o1[j] = f2bf(v * inv);
    }
    size_t ob = (size_t)(qt * 64 + q) * NFEAT + h * DK + ds;
    *reinterpret_cast<bf16x8*>(&ctxb[ob]) = o0;
    *reinterpret_cast<bf16x8*>(&ctxb[ob + 8]) = o1;
}

extern "C" void kernel_launch(void* const* d_in, const int* in_sizes, int n_in,
                              void* d_out, int out_size, void* d_ws, size_t ws_size,
                              hipStream_t stream) {
    const float* x   = (const float*)d_in[0];
    const float* Wq  = (const float*)d_in[1];
    const float* bq  = (const float*)d_in[2];
    const float* Wk  = (const float*)d_in[3];
    const float* bk  = (const float*)d_in[4];
    const float* Wv  = (const float*)d_in[5];
    const float* bv  = (const float*)d_in[6];
    const float* Wo  = (const float*)d_in[7];
    const float* bo  = (const float*)d_in[8];
    const float* kc  = (const float*)d_in[9];
    const float* vc  = (const float*)d_in[10];
    const int*   bt  = (const int*)d_in[11];
    const int*   so  = (const int*)d_in[12];

    short* Wt   = (short*)d_ws;                       // 4M bf16
    short* qbuf = Wt + (size_t)4096 * 1024;           // 1M bf16
    short* kg   = qbuf + (size_t)1024 * 1024;         // 4M bf16
    short* vtb  = kg + (size_t)NHEAD * MAXTOK * DK;   // 4M bf16
    float* pacc = (float*)(vtb + (size_t)NHEAD * DK * MAXTOK);  // NSPLIT*256*4224 f32
    short* ctxb = (short*)(pacc + (size_t)NSPLIT * 256 * 4224); // 1M bf16

    pack_kernel<<<dim3(1792), 256, 0, stream>>>(Wq, Wk, Wv, Wo, kc, vc, bt, so,
                                                Wt, kg, vtb);
    qkv_gemm<<<dim3(24, 16), 256, 0, stream>>>(x, Wt, bq, bk, bv, so,
                                               qbuf, kg, vtb);
    attn_mfma<<<dim3(16, 16, NSPLIT), 128, 0, stream>>>(qbuf, kg, vtb, so, pacc);
    merge_ctx<<<dim3(16, 16), 256, 0, stream>>>(pacc, ctxb);
    out_gemm<<<dim3(16, 16), 256, 0, stream>>>(ctxb, Wt, bo, (float*)d_out);
}

// Round 18
// 100.637 us; speedup vs baseline: 1.1975x; 1.1975x over previous
//
#include <hip/hip_runtime.h>
#include <hip/hip_bf16.h>

#define NFEAT 1024
#define NHEAD 16
#define DK 64
#define TCHUNK 1024
#define MAXTOK 4096
#define NSPLIT 4

using bf16x8 = __attribute__((ext_vector_type(8))) short;
using f32x4  = __attribute__((ext_vector_type(4))) float;
using f32x16 = __attribute__((ext_vector_type(16))) float;
using u32x4  = __attribute__((ext_vector_type(4))) unsigned int;

__device__ __forceinline__ short f2bf(float f) {
    __hip_bfloat16 h = __float2bfloat16(f);
    return *reinterpret_cast<short*>(&h);
}

__device__ __forceinline__ float exp2fast(float x) {
    return __builtin_amdgcn_exp2f(x);
}

__device__ __forceinline__ unsigned int pack2bf(float a, float b) {
    unsigned int lo = (unsigned int)(unsigned short)f2bf(a);
    unsigned int hi = (unsigned int)(unsigned short)f2bf(b);
    return lo | (hi << 16);
}

// log2(e)/sqrt(DK): folds the 1/sqrt(64) and the exp->exp2 conversion
#define QSCALE 0.1803368801f

// ---------------------------------------------------------------------------
// pack: blocks [0,1024): transpose+convert W{q,k,v,o} -> Wt[4096 n][1024 k]
//       blocks [1024,1152): convert x -> xb bf16
//       blocks [1152,1920): gather cache tokens -> kg[h][tok][d], vt[h][d][tok]
// ---------------------------------------------------------------------------
__global__ __launch_bounds__(256) void pack_kernel(
    const float* __restrict__ x,
    const float* __restrict__ Wq, const float* __restrict__ Wk,
    const float* __restrict__ Wv, const float* __restrict__ Wo,
    const float* __restrict__ kc, const float* __restrict__ vc,
    const int* __restrict__ btab, const int* __restrict__ soff,
    short* __restrict__ xb, short* __restrict__ Wt,
    short* __restrict__ kg, short* __restrict__ vt) {
    const int b = blockIdx.x;
    const int t = threadIdx.x;
    if (b < 1024) {
        __shared__ short T[64][72];
        const int w = b >> 8, tile = b & 255;
        const int k0 = (tile >> 4) << 6, n0 = (tile & 15) << 6;
        const float* W = (w == 0) ? Wq : (w == 1) ? Wk : (w == 2) ? Wv : Wo;
        const int r = t >> 2, cs = (t & 3) << 4;
        #pragma unroll
        for (int u = 0; u < 4; ++u) {
            float4 v = *reinterpret_cast<const float4*>(
                &W[(size_t)(k0 + r) * NFEAT + n0 + cs + u * 4]);
            T[cs + u * 4 + 0][r] = f2bf(v.x);
            T[cs + u * 4 + 1][r] = f2bf(v.y);
            T[cs + u * 4 + 2][r] = f2bf(v.z);
            T[cs + u * 4 + 3][r] = f2bf(v.w);
        }
        __syncthreads();
        const int c = t >> 2, rs = (t & 3) << 4;
        bf16x8 a0 = *reinterpret_cast<const bf16x8*>(&T[c][rs]);
        bf16x8 a1 = *reinterpret_cast<const bf16x8*>(&T[c][rs + 8]);
        size_t drow = (size_t)(w * 1024 + n0 + c) * NFEAT + k0 + rs;
        *reinterpret_cast<bf16x8*>(&Wt[drow]) = a0;
        *reinterpret_cast<bf16x8*>(&Wt[drow + 8]) = a1;
    } else if (b < 1152) {
        const int e0 = ((b - 1024) * 256 + t) * 32;
        #pragma unroll
        for (int u = 0; u < 4; ++u) {
            float4 v0 = *reinterpret_cast<const float4*>(&x[e0 + u * 8]);
            float4 v1 = *reinterpret_cast<const float4*>(&x[e0 + u * 8 + 4]);
            bf16x8 o;
            o[0] = f2bf(v0.x); o[1] = f2bf(v0.y); o[2] = f2bf(v0.z); o[3] = f2bf(v0.w);
            o[4] = f2bf(v1.x); o[5] = f2bf(v1.y); o[6] = f2bf(v1.z); o[7] = f2bf(v1.w);
            *reinterpret_cast<bf16x8*>(&xb[e0 + u * 8]) = o;
        }
    } else {
        // cache-token gather (tokens [0, offset))
        __shared__ short TV[64][72];
        const int cb = b - 1152;
        const int h = cb & 15;
        const int t0 = (cb >> 4) << 6;
        const int offset = soff[0];
        const int row = t >> 2, ds = (t & 3) << 4;
        const int tok = t0 + row;
        short kv[16], vv[16];
        if (tok < offset) {
            int phys = btab[tok >> 5];
            size_t base = ((size_t)(phys * 32 + (tok & 31)) * NHEAD + h) * DK + ds;
            #pragma unroll
            for (int u = 0; u < 4; ++u) {
                float4 kf = *reinterpret_cast<const float4*>(&kc[base + u * 4]);
                float4 vf = *reinterpret_cast<const float4*>(&vc[base + u * 4]);
                kv[u * 4 + 0] = f2bf(kf.x); kv[u * 4 + 1] = f2bf(kf.y);
                kv[u * 4 + 2] = f2bf(kf.z); kv[u * 4 + 3] = f2bf(kf.w);
                vv[u * 4 + 0] = f2bf(vf.x); vv[u * 4 + 1] = f2bf(vf.y);
                vv[u * 4 + 2] = f2bf(vf.z); vv[u * 4 + 3] = f2bf(vf.w);
            }
        } else {
            #pragma unroll
            for (int e = 0; e < 16; ++e) { kv[e] = 0; vv[e] = 0; }
        }
        {
            bf16x8 a, bb;
            #pragma unroll
            for (int e = 0; e < 8; ++e) { a[e] = kv[e]; bb[e] = kv[8 + e]; }
            size_t kb = ((size_t)h * MAXTOK + tok) * DK + ds;
            *reinterpret_cast<bf16x8*>(&kg[kb]) = a;
            *reinterpret_cast<bf16x8*>(&kg[kb + 8]) = bb;
        }
        #pragma unroll
        for (int e = 0; e < 16; ++e) TV[ds + e][row] = vv[e];
        __syncthreads();
        {
            const int d = t >> 2, ts = (t & 3) << 4;
            bf16x8 a = *reinterpret_cast<const bf16x8*>(&TV[d][ts]);
            bf16x8 bb = *reinterpret_cast<const bf16x8*>(&TV[d][ts + 8]);
            size_t vb = ((size_t)h * DK + d) * MAXTOK + t0 + ts;
            *reinterpret_cast<bf16x8*>(&vt[vb]) = a;
            *reinterpret_cast<bf16x8*>(&vt[vb + 8]) = bb;
        }
    }
}

// ---------------------------------------------------------------------------
// QKV MFMA GEMM (64x128 tile, 384 blocks — best measured). sel==0 -> qbuf
// (scaled); sel==1 -> kg new-token region; sel==2 -> vt (transposed scatter).
// ---------------------------------------------------------------------------
__global__ __launch_bounds__(256) void qkv_gemm(
    const short* __restrict__ xb, const short* __restrict__ Wt,
    const float* __restrict__ bq, const float* __restrict__ bk,
    const float* __restrict__ bv, const int* __restrict__ soff,
    short* __restrict__ qbuf, short* __restrict__ kg, short* __restrict__ vt) {
    __shared__ short As[64][72];
    __shared__ short Bs[128][72];
    const int tid = threadIdx.x;
    const int lane = tid & 63;
    const int w = tid >> 6;
    const int l15 = lane & 15, lg = lane >> 4;
    const int wr = w >> 1, wc = w & 1;
    const int m0 = blockIdx.y << 6, n0 = blockIdx.x << 7;
    const int sel = n0 >> 10;
    const float* bias = (sel == 0) ? bq : (sel == 1) ? bk : bv;

    f32x4 acc[2][4];
    #pragma unroll
    for (int i = 0; i < 2; ++i)
        #pragma unroll
        for (int j = 0; j < 4; ++j) acc[i][j] = (f32x4){0.f, 0.f, 0.f, 0.f};

    for (int k0 = 0; k0 < NFEAT; k0 += 64) {
        #pragma unroll
        for (int r = 0; r < 2; ++r) {
            int f = tid + (r << 8);
            int row = f >> 3, kc = (f & 7) << 3;
            *reinterpret_cast<bf16x8*>(&As[row][kc]) =
                *reinterpret_cast<const bf16x8*>(&xb[(size_t)(m0 + row) * NFEAT + k0 + kc]);
        }
        #pragma unroll
        for (int r = 0; r < 4; ++r) {
            int f = tid + (r << 8);
            int row = f >> 3, kc = (f & 7) << 3;
            *reinterpret_cast<bf16x8*>(&Bs[row][kc]) =
                *reinterpret_cast<const bf16x8*>(&Wt[(size_t)(n0 + row) * NFEAT + k0 + kc]);
        }
        __syncthreads();
        #pragma unroll
        for (int kk = 0; kk < 2; ++kk) {
            bf16x8 am[2], bn[4];
            #pragma unroll
            for (int mi = 0; mi < 2; ++mi)
                am[mi] = *reinterpret_cast<const bf16x8*>(
                    &As[wr * 32 + mi * 16 + l15][kk * 32 + lg * 8]);
            #pragma unroll
            for (int ni = 0; ni < 4; ++ni)
                bn[ni] = *reinterpret_cast<const bf16x8*>(
                    &Bs[wc * 64 + ni * 16 + l15][kk * 32 + lg * 8]);
            #pragma unroll
            for (int mi = 0; mi < 2; ++mi)
                #pragma unroll
                for (int ni = 0; ni < 4; ++ni)
                    acc[mi][ni] = __builtin_amdgcn_mfma_f32_16x16x32_bf16(
                        am[mi], bn[ni], acc[mi][ni], 0, 0, 0);
        }
        __syncthreads();
    }
    const int offs = soff[0];
    #pragma unroll
    for (int mi = 0; mi < 2; ++mi)
        #pragma unroll
        for (int rr = 0; rr < 4; ++rr) {
            int m = m0 + wr * 32 + mi * 16 + lg * 4 + rr;
            #pragma unroll
            for (int ni = 0; ni < 4; ++ni) {
                int n = n0 + wc * 64 + ni * 16 + l15;
                float v = acc[mi][ni][rr] + bias[n & 1023];
                if (sel == 0) {
                    qbuf[(size_t)m * NFEAT + n] = f2bf(v * QSCALE);
                } else if (sel == 1) {
                    int nn = n - 1024, hh = nn >> 6, dd = nn & 63;
                    kg[((size_t)hh * MAXTOK + offs + m) * DK + dd] = f2bf(v);
                } else {
                    int nn = n - 2048, hh = nn >> 6, dd = nn & 63;
                    vt[((size_t)hh * DK + dd) * MAXTOK + offs + m] = f2bf(v);
                }
            }
        }
}

// ---------------------------------------------------------------------------
// Output MFMA GEMM: out[1024][1024] f32 = ctxb @ Wo + bo.
// ---------------------------------------------------------------------------
__global__ __launch_bounds__(256) void out_gemm(
    const short* __restrict__ ctxb, const short* __restrict__ Wt,
    const float* __restrict__ bo, float* __restrict__ out) {
    __shared__ short As[64][72];
    __shared__ short Bs[64][72];
    const int tid = threadIdx.x;
    const int lane = tid & 63;
    const int w = tid >> 6;
    const int l15 = lane & 15, lg = lane >> 4;
    const int wr = w >> 1, wc = w & 1;
    const int m0 = blockIdx.y << 6, n0 = blockIdx.x << 6;

    f32x4 acc[2][2];
    #pragma unroll
    for (int i = 0; i < 2; ++i)
        #pragma unroll
        for (int j = 0; j < 2; ++j) acc[i][j] = (f32x4){0.f, 0.f, 0.f, 0.f};

    for (int k0 = 0; k0 < NFEAT; k0 += 64) {
        #pragma unroll
        for (int r = 0; r < 2; ++r) {
            int f = tid + (r << 8);
            int row = f >> 3, kc = (f & 7) << 3;
            *reinterpret_cast<bf16x8*>(&As[row][kc]) =
                *reinterpret_cast<const bf16x8*>(&ctxb[(size_t)(m0 + row) * NFEAT + k0 + kc]);
            *reinterpret_cast<bf16x8*>(&Bs[row][kc]) =
                *reinterpret_cast<const bf16x8*>(
                    &Wt[(size_t)(3072 + n0 + row) * NFEAT + k0 + kc]);
        }
        __syncthreads();
        #pragma unroll
        for (int kk = 0; kk < 2; ++kk) {
            bf16x8 am[2], bn[2];
            #pragma unroll
            for (int mi = 0; mi < 2; ++mi)
                am[mi] = *reinterpret_cast<const bf16x8*>(
                    &As[wr * 32 + mi * 16 + l15][kk * 32 + lg * 8]);
            #pragma unroll
            for (int ni = 0; ni < 2; ++ni)
                bn[ni] = *reinterpret_cast<const bf16x8*>(
                    &Bs[wc * 32 + ni * 16 + l15][kk * 32 + lg * 8]);
            #pragma unroll
            for (int mi = 0; mi < 2; ++mi)
                #pragma unroll
                for (int ni = 0; ni < 2; ++ni)
                    acc[mi][ni] = __builtin_amdgcn_mfma_f32_16x16x32_bf16(
                        am[mi], bn[ni], acc[mi][ni], 0, 0, 0);
        }
        __syncthreads();
    }
    #pragma unroll
    for (int mi = 0; mi < 2; ++mi)
        #pragma unroll
        for (int rr = 0; rr < 4; ++rr) {
            int m = m0 + wr * 32 + mi * 16 + lg * 4 + rr;
            #pragma unroll
            for (int ni = 0; ni < 2; ++ni) {
                int n = n0 + wc * 32 + ni * 16 + l15;
                out[(size_t)m * NFEAT + n] = acc[mi][ni][rr] + bo[n];
            }
        }
}

// ---------------------------------------------------------------------------
// MFMA flash attention v16 — swapped-operand 32x32, P fully in-register.
// Grid (16 h, 16 qt, 4 z), block 128 (2 waves), each wave 32 q-rows.
// S^T = mfma_32x32x16(K, Q): lane holds col q=lane&31, 16 rows
// crow(r,hi)=(r&3)+8(r>>2)+4hi per tok-half. Softmax: in-lane max/sum +
// one shfl_xor(32). P->PV A-frag via pack + 2 shfl_xor(32) + 4 selects
// per k-slot. No Ps LDS, no ones-MFMA. merge_ctx unchanged.
// ---------------------------------------------------------------------------
__global__ __launch_bounds__(128, 2) void attn_mfma(
    const short* __restrict__ qbuf, const short* __restrict__ kg,
    const short* __restrict__ vt, const int* __restrict__ soff,
    float* __restrict__ pacc) {
    __shared__ short Ks[64][72];
    __shared__ short Vs[64][72];   // [d][tok]

    const int tid = threadIdx.x;
    const int lane = tid & 63;
    const int w = tid >> 6;        // 0/1
    const int l31 = lane & 31;
    const int hi = lane >> 5;
    const int h = blockIdx.x;
    const int qt = blockIdx.y;
    const int z = blockIdx.z;
    const int offset = soff[0];
    const int total = offset + TCHUNK;
    const int ntiles = (total + 63) >> 6;
    const int NT = (ntiles + NSPLIT - 1) / NSPLIT;
    const int tbase = z * NT;
    const int tend = min(tbase + NT, ntiles);

    const int srow = tid >> 1;           // 0..63 (tok for K, d for V)
    const int sseg = (tid & 1) << 5;     // 0 or 32

    const short* kbase = kg + (size_t)h * MAXTOK * DK;
    const short* vbase = vt + (size_t)h * DK * MAXTOK;

    // Q B-fragments: q = qt*64 + w*32 + l31, d = 16j + 8hi + e
    bf16x8 qf[4];
    {
        size_t qrow = (size_t)(qt * 64 + w * 32 + l31) * NFEAT + h * DK;
        #pragma unroll
        for (int j = 0; j < 4; ++j)
            qf[j] = *reinterpret_cast<const bf16x8*>(&qbuf[qrow + j * 16 + hi * 8]);
    }

    float m = -1e30f, lsum = 0.f;
    f32x16 accA, accB;
    #pragma unroll
    for (int i = 0; i < 16; ++i) { accA[i] = 0.f; accB[i] = 0.f; }

    bf16x8 kr[4], vr[4];
    if (tbase < tend) {
        int tok0 = tbase << 6;
        #pragma unroll
        for (int j = 0; j < 4; ++j) {
            kr[j] = *reinterpret_cast<const bf16x8*>(
                &kbase[(size_t)(tok0 + srow) * DK + sseg + j * 8]);
            vr[j] = *reinterpret_cast<const bf16x8*>(
                &vbase[(size_t)srow * MAXTOK + tok0 + sseg + j * 8]);
        }
    }

    for (int t = tbase; t < tend; ++t) {
        __syncthreads();   // previous tile fully consumed
        #pragma unroll
        for (int j = 0; j < 4; ++j) {
            *reinterpret_cast<bf16x8*>(&Ks[srow][sseg + j * 8]) = kr[j];
            *reinterpret_cast<bf16x8*>(&Vs[srow][sseg + j * 8]) = vr[j];
        }
        __syncthreads();   // staged tile visible
        if (t + 1 < tend) {   // prefetch next tile into regs
            int tok0 = (t + 1) << 6;
            #pragma unroll
            for (int j = 0; j < 4; ++j) {
                kr[j] = *reinterpret_cast<const bf16x8*>(
                    &kbase[(size_t)(tok0 + srow) * DK + sseg + j * 8]);
                vr[j] = *reinterpret_cast<const bf16x8*>(
                    &vbase[(size_t)srow * MAXTOK + tok0 + sseg + j * 8]);
            }
        }

        const int kt0 = t << 6;
        // ---- S^T = K * Q^T (two tok-halves, 4 d-steps) ----
        f32x16 st0, st1;
        #pragma unroll
        for (int i = 0; i < 16; ++i) { st0[i] = 0.f; st1[i] = 0.f; }
        __builtin_amdgcn_s_setprio(1);
        #pragma unroll
        for (int j = 0; j < 4; ++j) {
            bf16x8 ka0 = *reinterpret_cast<const bf16x8*>(&Ks[l31][j * 16 + hi * 8]);
            bf16x8 ka1 = *reinterpret_cast<const bf16x8*>(&Ks[32 + l31][j * 16 + hi * 8]);
            st0 = __builtin_amdgcn_mfma_f32_32x32x16_bf16(ka0, qf[j], st0, 0, 0, 0);
            st1 = __builtin_amdgcn_mfma_f32_32x32x16_bf16(ka1, qf[j], st1, 0, 0, 0);
        }
        __builtin_amdgcn_s_setprio(0);
        // ---- mask (uniform last-tile branch) ----
        if (kt0 + 64 > total) {
            #pragma unroll
            for (int r = 0; r < 16; ++r) {
                int crow = (r & 3) + 8 * (r >> 2) + 4 * hi;
                if (kt0 + crow >= total) st0[r] = -1e30f;
                if (kt0 + 32 + crow >= total) st1[r] = -1e30f;
            }
        }
        // ---- in-lane row max + cross-half ----
        float lm = st0[0];
        #pragma unroll
        for (int r = 1; r < 16; ++r) lm = fmaxf(lm, st0[r]);
        #pragma unroll
        for (int r = 0; r < 16; ++r) lm = fmaxf(lm, st1[r]);
        float full = fmaxf(lm, __shfl_xor(lm, 32));
        // ---- defer-max ----
        if (!__all(full <= m + 8.f)) {
            float mn = fmaxf(m, full);
            float sc = exp2fast(m - mn);
            m = mn;
            lsum *= sc;
            #pragma unroll
            for (int r = 0; r < 16; ++r) {
                int crow = (r & 3) + 8 * (r >> 2) + 4 * hi;
                float scr = __shfl(sc, crow);
                accA[r] *= scr;
                accB[r] *= scr;
            }
        }
        // ---- P = exp2(s - m), pack to bf16 pairs, accumulate row-sum ----
        unsigned int pk0[8], pk1[8];
        #pragma unroll
        for (int c = 0; c < 8; ++c) {
            float a0 = exp2fast(st0[2 * c] - m);
            float a1 = exp2fast(st0[2 * c + 1] - m);
            float b0 = exp2fast(st1[2 * c] - m);
            float b1 = exp2fast(st1[2 * c + 1] - m);
            lsum += (a0 + a1) + (b0 + b1);
            pk0[c] = pack2bf(a0, a1);
            pk1[c] = pack2bf(b0, b1);
        }
        // ---- PV: build PA per 16-k slot via cross-half exchange ----
        #pragma unroll
        for (int ks = 0; ks < 4; ++ks) {
            const int b4 = (ks & 1) * 4;
            unsigned int w0, w1, w2, w3;
            if (ks < 2) { w0 = pk0[b4]; w1 = pk0[b4 + 1]; w2 = pk0[b4 + 2]; w3 = pk0[b4 + 3]; }
            else        { w0 = pk1[b4]; w1 = pk1[b4 + 1]; w2 = pk1[b4 + 2]; w3 = pk1[b4 + 3]; }
            unsigned int x0 = __shfl_xor(hi ? w0 : w2, 32);
            unsigned int x1 = __shfl_xor(hi ? w1 : w3, 32);
            u32x4 uu;
            uu[0] = hi ? x0 : w0;
            uu[1] = hi ? x1 : w1;
            uu[2] = hi ? w2 : x0;
            uu[3] = hi ? w3 : x1;
            bf16x8 pa = __builtin_bit_cast(bf16x8, uu);
            bf16x8 bv0 = *reinterpret_cast<const bf16x8*>(&Vs[l31][ks * 16 + hi * 8]);
            bf16x8 bv1 = *reinterpret_cast<const bf16x8*>(&Vs[32 + l31][ks * 16 + hi * 8]);
            __builtin_amdgcn_s_setprio(1);
            accA = __builtin_amdgcn_mfma_f32_32x32x16_bf16(pa, bv0, accA, 0, 0, 0);
            accB = __builtin_amdgcn_mfma_f32_32x32x16_bf16(pa, bv1, accB, 0, 0, 0);
            __builtin_amdgcn_s_setprio(0);
        }
    }

    // ---- epilogue: combine halves' row-sum, write partials ----
    float lt = lsum + __shfl_xor(lsum, 32);
    const size_t pbase = (((size_t)z * NHEAD + h) * 16 + qt) * 4224;
    if (hi == 0) {
        int q = w * 32 + l31;
        pacc[pbase + 4096 + q] = m;
        pacc[pbase + 4160 + q] = lt;
    }
    #pragma unroll
    for (int r = 0; r < 16; ++r) {
        int crow = (r & 3) + 8 * (r >> 2) + 4 * hi;
        int q = w * 32 + crow;
        pacc[pbase + q * 64 + l31] = accA[r];
        pacc[pbase + q * 64 + 32 + l31] = accB[r];
    }
}

// ---------------------------------------------------------------------------
// merge NSPLIT split partials -> ctxb bf16 [1024 t][1024 (h*64+d)]
// ---------------------------------------------------------------------------
__global__ __launch_bounds__(256) void merge_ctx(
    const float* __restrict__ pacc, short* __restrict__ ctxb) {
    const int h = blockIdx.x, qt = blockIdx.y;
    const int t = threadIdx.x;
    const int q = t >> 2, ds = (t & 3) << 4;
    size_t b[NSPLIT];
    float mz[NSPLIT], lz[NSPLIT];
    float M = -1e30f;
    #pragma unroll
    for (int z = 0; z < NSPLIT; ++z) {
        b[z] = (((size_t)z * NHEAD + h) * 16 + qt) * 4224;
        mz[z] = pacc[b[z] + 4096 + q];
        lz[z] = pacc[b[z] + 4160 + q];
        M = fmaxf(M, mz[z]);
    }
    float L = 0.f, ez[NSPLIT];
    #pragma unroll
    for (int z = 0; z < NSPLIT; ++z) {
        ez[z] = __builtin_amdgcn_exp2f(mz[z] - M);
        L += lz[z] * ez[z];
    }
    float inv = 1.f / L;
    bf16x8 o0, o1;
    #pragma unroll
    for (int j = 0; j < 8; ++j) {
        float v = 0.f;
        #pragma unroll
        for (int z = 0; z < NSPLIT; ++z)
            v += pacc[b[z] + q * 64 + ds + j] * ez[z];
        o0[j] = f2bf(v * inv);
    }
    #pragma unroll
    for (int j = 0; j < 8; ++j) {
        float v = 0.f;
        #pragma unroll
        for (int z = 0; z < NSPLIT; ++z)
            v += pacc[b[z] + q * 64 + ds + 8 + j] * ez[z];
        o1[j] = f2bf(v * inv);
    }
    size_t ob = (size_t)(qt * 64 + q) * NFEAT + h * DK + ds;
    *reinterpret_cast<bf16x8*>(&ctxb[ob]) = o0;
    *reinterpret_cast<bf16x8*>(&ctxb[ob + 8]) = o1;
}

extern "C" void kernel_launch(void* const* d_in, const int* in_sizes, int n_in,
                              void* d_out, int out_size, void* d_ws, size_t ws_size,
                              hipStream_t stream) {
    const float* x   = (const float*)d_in[0];
    const float* Wq  = (const float*)d_in[1];
    const float* bq  = (const float*)d_in[2];
    const float* Wk  = (const float*)d_in[3];
    const float* bk  = (const float*)d_in[4];
    const float* Wv  = (const float*)d_in[5];
    const float* bv  = (const float*)d_in[6];
    const float* Wo  = (const float*)d_in[7];
    const float* bo  = (const float*)d_in[8];
    const float* kc  = (const float*)d_in[9];
    const float* vc  = (const float*)d_in[10];
    const int*   bt  = (const int*)d_in[11];
    const int*   so  = (const int*)d_in[12];

    short* xb   = (short*)d_ws;                       // 1M bf16
    short* Wt   = xb + (size_t)1024 * 1024;           // 4M bf16
    short* qbuf = Wt + (size_t)4096 * 1024;           // 1M bf16
    short* kg   = qbuf + (size_t)1024 * 1024;         // 4M bf16
    short* vtb  = kg + (size_t)NHEAD * MAXTOK * DK;   // 4M bf16
    float* pacc = (float*)(vtb + (size_t)NHEAD * DK * MAXTOK);  // NSPLIT*256*4224 f32
    short* ctxb = (short*)(pacc + (size_t)NSPLIT * 256 * 4224); // 1M bf16

    pack_kernel<<<dim3(1920), 256, 0, stream>>>(x, Wq, Wk, Wv, Wo, kc, vc, bt, so,
                                                xb, Wt, kg, vtb);
    qkv_gemm<<<dim3(24, 16), 256, 0, stream>>>(xb, Wt, bq, bk, bv, so,
                                               qbuf, kg, vtb);
    attn_mfma<<<dim3(16, 16, NSPLIT), 128, 0, stream>>>(qbuf, kg, vtb, so, pacc);
    merge_ctx<<<dim3(16, 16), 256, 0, stream>>>(pacc, ctxb);
    out_gemm<<<dim3(16, 16), 256, 0, stream>>>(ctxb, Wt, bo, (float*)d_out);
}

// Round 19
// 97.941 us; speedup vs baseline: 1.2304x; 1.0275x over previous
//
#include <hip/hip_runtime.h>
#include <hip/hip_bf16.h>

#define NFEAT 1024
#define NHEAD 16
#define DK 64
#define TCHUNK 1024
#define MAXTOK 4096
#define NSPLIT 4

using bf16x8 = __attribute__((ext_vector_type(8))) short;
using f32x4  = __attribute__((ext_vector_type(4))) float;
using f32x16 = __attribute__((ext_vector_type(16))) float;
using u32x4  = __attribute__((ext_vector_type(4))) unsigned int;

__device__ __forceinline__ short f2bf(float f) {
    __hip_bfloat16 h = __float2bfloat16(f);
    return *reinterpret_cast<short*>(&h);
}

__device__ __forceinline__ float bf2f(short s) {
    unsigned int u = ((unsigned int)(unsigned short)s) << 16;
    return __builtin_bit_cast(float, u);
}

__device__ __forceinline__ float exp2fast(float x) {
    return __builtin_amdgcn_exp2f(x);
}

__device__ __forceinline__ unsigned int pack2bf(float a, float b) {
    unsigned int lo = (unsigned int)(unsigned short)f2bf(a);
    unsigned int hi = (unsigned int)(unsigned short)f2bf(b);
    return lo | (hi << 16);
}

// log2(e)/sqrt(DK): folds the 1/sqrt(64) and the exp->exp2 conversion
#define QSCALE 0.1803368801f

// ---------------------------------------------------------------------------
// pack: blocks [0,1024): transpose+convert W{q,k,v,o} -> Wt[4096 n][1024 k]
//       blocks [1024,1152): convert x -> xb bf16
//       blocks [1152,1920): gather cache tokens -> kg[h][tok][d], vt[h][d][tok]
// ---------------------------------------------------------------------------
__global__ __launch_bounds__(256) void pack_kernel(
    const float* __restrict__ x,
    const float* __restrict__ Wq, const float* __restrict__ Wk,
    const float* __restrict__ Wv, const float* __restrict__ Wo,
    const float* __restrict__ kc, const float* __restrict__ vc,
    const int* __restrict__ btab, const int* __restrict__ soff,
    short* __restrict__ xb, short* __restrict__ Wt,
    short* __restrict__ kg, short* __restrict__ vt) {
    const int b = blockIdx.x;
    const int t = threadIdx.x;
    if (b < 1024) {
        __shared__ short T[64][72];
        const int w = b >> 8, tile = b & 255;
        const int k0 = (tile >> 4) << 6, n0 = (tile & 15) << 6;
        const float* W = (w == 0) ? Wq : (w == 1) ? Wk : (w == 2) ? Wv : Wo;
        const int r = t >> 2, cs = (t & 3) << 4;
        #pragma unroll
        for (int u = 0; u < 4; ++u) {
            float4 v = *reinterpret_cast<const float4*>(
                &W[(size_t)(k0 + r) * NFEAT + n0 + cs + u * 4]);
            T[cs + u * 4 + 0][r] = f2bf(v.x);
            T[cs + u * 4 + 1][r] = f2bf(v.y);
            T[cs + u * 4 + 2][r] = f2bf(v.z);
            T[cs + u * 4 + 3][r] = f2bf(v.w);
        }
        __syncthreads();
        const int c = t >> 2, rs = (t & 3) << 4;
        bf16x8 a0 = *reinterpret_cast<const bf16x8*>(&T[c][rs]);
        bf16x8 a1 = *reinterpret_cast<const bf16x8*>(&T[c][rs + 8]);
        size_t drow = (size_t)(w * 1024 + n0 + c) * NFEAT + k0 + rs;
        *reinterpret_cast<bf16x8*>(&Wt[drow]) = a0;
        *reinterpret_cast<bf16x8*>(&Wt[drow + 8]) = a1;
    } else if (b < 1152) {
        const int e0 = ((b - 1024) * 256 + t) * 32;
        #pragma unroll
        for (int u = 0; u < 4; ++u) {
            float4 v0 = *reinterpret_cast<const float4*>(&x[e0 + u * 8]);
            float4 v1 = *reinterpret_cast<const float4*>(&x[e0 + u * 8 + 4]);
            bf16x8 o;
            o[0] = f2bf(v0.x); o[1] = f2bf(v0.y); o[2] = f2bf(v0.z); o[3] = f2bf(v0.w);
            o[4] = f2bf(v1.x); o[5] = f2bf(v1.y); o[6] = f2bf(v1.z); o[7] = f2bf(v1.w);
            *reinterpret_cast<bf16x8*>(&xb[e0 + u * 8]) = o;
        }
    } else {
        // cache-token gather (tokens [0, offset))
        __shared__ short TV[64][72];
        const int cb = b - 1152;
        const int h = cb & 15;
        const int t0 = (cb >> 4) << 6;
        const int offset = soff[0];
        const int row = t >> 2, ds = (t & 3) << 4;
        const int tok = t0 + row;
        short kv[16], vv[16];
        if (tok < offset) {
            int phys = btab[tok >> 5];
            size_t base = ((size_t)(phys * 32 + (tok & 31)) * NHEAD + h) * DK + ds;
            #pragma unroll
            for (int u = 0; u < 4; ++u) {
                float4 kf = *reinterpret_cast<const float4*>(&kc[base + u * 4]);
                float4 vf = *reinterpret_cast<const float4*>(&vc[base + u * 4]);
                kv[u * 4 + 0] = f2bf(kf.x); kv[u * 4 + 1] = f2bf(kf.y);
                kv[u * 4 + 2] = f2bf(kf.z); kv[u * 4 + 3] = f2bf(kf.w);
                vv[u * 4 + 0] = f2bf(vf.x); vv[u * 4 + 1] = f2bf(vf.y);
                vv[u * 4 + 2] = f2bf(vf.z); vv[u * 4 + 3] = f2bf(vf.w);
            }
        } else {
            #pragma unroll
            for (int e = 0; e < 16; ++e) { kv[e] = 0; vv[e] = 0; }
        }
        {
            bf16x8 a, bb;
            #pragma unroll
            for (int e = 0; e < 8; ++e) { a[e] = kv[e]; bb[e] = kv[8 + e]; }
            size_t kb = ((size_t)h * MAXTOK + tok) * DK + ds;
            *reinterpret_cast<bf16x8*>(&kg[kb]) = a;
            *reinterpret_cast<bf16x8*>(&kg[kb + 8]) = bb;
        }
        #pragma unroll
        for (int e = 0; e < 16; ++e) TV[ds + e][row] = vv[e];
        __syncthreads();
        {
            const int d = t >> 2, ts = (t & 3) << 4;
            bf16x8 a = *reinterpret_cast<const bf16x8*>(&TV[d][ts]);
            bf16x8 bb = *reinterpret_cast<const bf16x8*>(&TV[d][ts + 8]);
            size_t vb = ((size_t)h * DK + d) * MAXTOK + t0 + ts;
            *reinterpret_cast<bf16x8*>(&vt[vb]) = a;
            *reinterpret_cast<bf16x8*>(&vt[vb + 8]) = bb;
        }
    }
}

// ---------------------------------------------------------------------------
// QKV MFMA GEMM (64x128 tile, 384 blocks — best measured). sel==0 -> qbuf
// (scaled); sel==1 -> kg new-token region; sel==2 -> vt (transposed scatter).
// ---------------------------------------------------------------------------
__global__ __launch_bounds__(256) void qkv_gemm(
    const short* __restrict__ xb, const short* __restrict__ Wt,
    const float* __restrict__ bq, const float* __restrict__ bk,
    const float* __restrict__ bv, const int* __restrict__ soff,
    short* __restrict__ qbuf, short* __restrict__ kg, short* __restrict__ vt) {
    __shared__ short As[64][72];
    __shared__ short Bs[128][72];
    const int tid = threadIdx.x;
    const int lane = tid & 63;
    const int w = tid >> 6;
    const int l15 = lane & 15, lg = lane >> 4;
    const int wr = w >> 1, wc = w & 1;
    const int m0 = blockIdx.y << 6, n0 = blockIdx.x << 7;
    const int sel = n0 >> 10;
    const float* bias = (sel == 0) ? bq : (sel == 1) ? bk : bv;

    f32x4 acc[2][4];
    #pragma unroll
    for (int i = 0; i < 2; ++i)
        #pragma unroll
        for (int j = 0; j < 4; ++j) acc[i][j] = (f32x4){0.f, 0.f, 0.f, 0.f};

    for (int k0 = 0; k0 < NFEAT; k0 += 64) {
        #pragma unroll
        for (int r = 0; r < 2; ++r) {
            int f = tid + (r << 8);
            int row = f >> 3, kc = (f & 7) << 3;
            *reinterpret_cast<bf16x8*>(&As[row][kc]) =
                *reinterpret_cast<const bf16x8*>(&xb[(size_t)(m0 + row) * NFEAT + k0 + kc]);
        }
        #pragma unroll
        for (int r = 0; r < 4; ++r) {
            int f = tid + (r << 8);
            int row = f >> 3, kc = (f & 7) << 3;
            *reinterpret_cast<bf16x8*>(&Bs[row][kc]) =
                *reinterpret_cast<const bf16x8*>(&Wt[(size_t)(n0 + row) * NFEAT + k0 + kc]);
        }
        __syncthreads();
        #pragma unroll
        for (int kk = 0; kk < 2; ++kk) {
            bf16x8 am[2], bn[4];
            #pragma unroll
            for (int mi = 0; mi < 2; ++mi)
                am[mi] = *reinterpret_cast<const bf16x8*>(
                    &As[wr * 32 + mi * 16 + l15][kk * 32 + lg * 8]);
            #pragma unroll
            for (int ni = 0; ni < 4; ++ni)
                bn[ni] = *reinterpret_cast<const bf16x8*>(
                    &Bs[wc * 64 + ni * 16 + l15][kk * 32 + lg * 8]);
            #pragma unroll
            for (int mi = 0; mi < 2; ++mi)
                #pragma unroll
                for (int ni = 0; ni < 4; ++ni)
                    acc[mi][ni] = __builtin_amdgcn_mfma_f32_16x16x32_bf16(
                        am[mi], bn[ni], acc[mi][ni], 0, 0, 0);
        }
        __syncthreads();
    }
    const int offs = soff[0];
    #pragma unroll
    for (int mi = 0; mi < 2; ++mi)
        #pragma unroll
        for (int rr = 0; rr < 4; ++rr) {
            int m = m0 + wr * 32 + mi * 16 + lg * 4 + rr;
            #pragma unroll
            for (int ni = 0; ni < 4; ++ni) {
                int n = n0 + wc * 64 + ni * 16 + l15;
                float v = acc[mi][ni][rr] + bias[n & 1023];
                if (sel == 0) {
                    qbuf[(size_t)m * NFEAT + n] = f2bf(v * QSCALE);
                } else if (sel == 1) {
                    int nn = n - 1024, hh = nn >> 6, dd = nn & 63;
                    kg[((size_t)hh * MAXTOK + offs + m) * DK + dd] = f2bf(v);
                } else {
                    int nn = n - 2048, hh = nn >> 6, dd = nn & 63;
                    vt[((size_t)hh * DK + dd) * MAXTOK + offs + m] = f2bf(v);
                }
            }
        }
}

// ---------------------------------------------------------------------------
// Output MFMA GEMM: out[1024][1024] f32 = ctxb @ Wo + bo.
// ---------------------------------------------------------------------------
__global__ __launch_bounds__(256) void out_gemm(
    const short* __restrict__ ctxb, const short* __restrict__ Wt,
    const float* __restrict__ bo, float* __restrict__ out) {
    __shared__ short As[64][72];
    __shared__ short Bs[64][72];
    const int tid = threadIdx.x;
    const int lane = tid & 63;
    const int w = tid >> 6;
    const int l15 = lane & 15, lg = lane >> 4;
    const int wr = w >> 1, wc = w & 1;
    const int m0 = blockIdx.y << 6, n0 = blockIdx.x << 6;

    f32x4 acc[2][2];
    #pragma unroll
    for (int i = 0; i < 2; ++i)
        #pragma unroll
        for (int j = 0; j < 2; ++j) acc[i][j] = (f32x4){0.f, 0.f, 0.f, 0.f};

    for (int k0 = 0; k0 < NFEAT; k0 += 64) {
        #pragma unroll
        for (int r = 0; r < 2; ++r) {
            int f = tid + (r << 8);
            int row = f >> 3, kc = (f & 7) << 3;
            *reinterpret_cast<bf16x8*>(&As[row][kc]) =
                *reinterpret_cast<const bf16x8*>(&ctxb[(size_t)(m0 + row) * NFEAT + k0 + kc]);
            *reinterpret_cast<bf16x8*>(&Bs[row][kc]) =
                *reinterpret_cast<const bf16x8*>(
                    &Wt[(size_t)(3072 + n0 + row) * NFEAT + k0 + kc]);
        }
        __syncthreads();
        #pragma unroll
        for (int kk = 0; kk < 2; ++kk) {
            bf16x8 am[2], bn[2];
            #pragma unroll
            for (int mi = 0; mi < 2; ++mi)
                am[mi] = *reinterpret_cast<const bf16x8*>(
                    &As[wr * 32 + mi * 16 + l15][kk * 32 + lg * 8]);
            #pragma unroll
            for (int ni = 0; ni < 2; ++ni)
                bn[ni] = *reinterpret_cast<const bf16x8*>(
                    &Bs[wc * 32 + ni * 16 + l15][kk * 32 + lg * 8]);
            #pragma unroll
            for (int mi = 0; mi < 2; ++mi)
                #pragma unroll
                for (int ni = 0; ni < 2; ++ni)
                    acc[mi][ni] = __builtin_amdgcn_mfma_f32_16x16x32_bf16(
                        am[mi], bn[ni], acc[mi][ni], 0, 0, 0);
        }
        __syncthreads();
    }
    #pragma unroll
    for (int mi = 0; mi < 2; ++mi)
        #pragma unroll
        for (int rr = 0; rr < 4; ++rr) {
            int m = m0 + wr * 32 + mi * 16 + lg * 4 + rr;
            #pragma unroll
            for (int ni = 0; ni < 2; ++ni) {
                int n = n0 + wc * 32 + ni * 16 + l15;
                out[(size_t)m * NFEAT + n] = acc[mi][ni][rr] + bo[n];
            }
        }
}

// ---------------------------------------------------------------------------
// MFMA flash attention v19 — v16 structure, partials stored as bf16.
// Grid (16 h, 16 qt, 4 z), block 128 (2 waves), each wave 32 q-rows.
// Unnormalized accs -> paccb (bf16); m/l -> pml (f32). Halves split-partial
// HBM traffic (attn WRITE 16.9->8.4 MB, merge FETCH 17->8.6 MB).
// ---------------------------------------------------------------------------
__global__ __launch_bounds__(128, 2) void attn_mfma(
    const short* __restrict__ qbuf, const short* __restrict__ kg,
    const short* __restrict__ vt, const int* __restrict__ soff,
    short* __restrict__ paccb, float* __restrict__ pml) {
    __shared__ short Ks[64][72];
    __shared__ short Vs[64][72];   // [d][tok]

    const int tid = threadIdx.x;
    const int lane = tid & 63;
    const int w = tid >> 6;        // 0/1
    const int l31 = lane & 31;
    const int hi = lane >> 5;
    const int h = blockIdx.x;
    const int qt = blockIdx.y;
    const int z = blockIdx.z;
    const int offset = soff[0];
    const int total = offset + TCHUNK;
    const int ntiles = (total + 63) >> 6;
    const int NT = (ntiles + NSPLIT - 1) / NSPLIT;
    const int tbase = z * NT;
    const int tend = min(tbase + NT, ntiles);

    const int srow = tid >> 1;           // 0..63 (tok for K, d for V)
    const int sseg = (tid & 1) << 5;     // 0 or 32

    const short* kbase = kg + (size_t)h * MAXTOK * DK;
    const short* vbase = vt + (size_t)h * DK * MAXTOK;

    // Q B-fragments: q = qt*64 + w*32 + l31, d = 16j + 8hi + e
    bf16x8 qf[4];
    {
        size_t qrow = (size_t)(qt * 64 + w * 32 + l31) * NFEAT + h * DK;
        #pragma unroll
        for (int j = 0; j < 4; ++j)
            qf[j] = *reinterpret_cast<const bf16x8*>(&qbuf[qrow + j * 16 + hi * 8]);
    }

    float m = -1e30f, lsum = 0.f;
    f32x16 accA, accB;
    #pragma unroll
    for (int i = 0; i < 16; ++i) { accA[i] = 0.f; accB[i] = 0.f; }

    bf16x8 kr[4], vr[4];
    if (tbase < tend) {
        int tok0 = tbase << 6;
        #pragma unroll
        for (int j = 0; j < 4; ++j) {
            kr[j] = *reinterpret_cast<const bf16x8*>(
                &kbase[(size_t)(tok0 + srow) * DK + sseg + j * 8]);
            vr[j] = *reinterpret_cast<const bf16x8*>(
                &vbase[(size_t)srow * MAXTOK + tok0 + sseg + j * 8]);
        }
    }

    for (int t = tbase; t < tend; ++t) {
        __syncthreads();   // previous tile fully consumed
        #pragma unroll
        for (int j = 0; j < 4; ++j) {
            *reinterpret_cast<bf16x8*>(&Ks[srow][sseg + j * 8]) = kr[j];
            *reinterpret_cast<bf16x8*>(&Vs[srow][sseg + j * 8]) = vr[j];
        }
        __syncthreads();   // staged tile visible
        if (t + 1 < tend) {   // prefetch next tile into regs
            int tok0 = (t + 1) << 6;
            #pragma unroll
            for (int j = 0; j < 4; ++j) {
                kr[j] = *reinterpret_cast<const bf16x8*>(
                    &kbase[(size_t)(tok0 + srow) * DK + sseg + j * 8]);
                vr[j] = *reinterpret_cast<const bf16x8*>(
                    &vbase[(size_t)srow * MAXTOK + tok0 + sseg + j * 8]);
            }
        }

        const int kt0 = t << 6;
        // ---- S^T = K * Q^T (two tok-halves, 4 d-steps) ----
        f32x16 st0, st1;
        #pragma unroll
        for (int i = 0; i < 16; ++i) { st0[i] = 0.f; st1[i] = 0.f; }
        __builtin_amdgcn_s_setprio(1);
        #pragma unroll
        for (int j = 0; j < 4; ++j) {
            bf16x8 ka0 = *reinterpret_cast<const bf16x8*>(&Ks[l31][j * 16 + hi * 8]);
            bf16x8 ka1 = *reinterpret_cast<const bf16x8*>(&Ks[32 + l31][j * 16 + hi * 8]);
            st0 = __builtin_amdgcn_mfma_f32_32x32x16_bf16(ka0, qf[j], st0, 0, 0, 0);
            st1 = __builtin_amdgcn_mfma_f32_32x32x16_bf16(ka1, qf[j], st1, 0, 0, 0);
        }
        __builtin_amdgcn_s_setprio(0);
        // ---- mask (uniform last-tile branch) ----
        if (kt0 + 64 > total) {
            #pragma unroll
            for (int r = 0; r < 16; ++r) {
                int crow = (r & 3) + 8 * (r >> 2) + 4 * hi;
                if (kt0 + crow >= total) st0[r] = -1e30f;
                if (kt0 + 32 + crow >= total) st1[r] = -1e30f;
            }
        }
        // ---- in-lane row max + cross-half ----
        float lm = st0[0];
        #pragma unroll
        for (int r = 1; r < 16; ++r) lm = fmaxf(lm, st0[r]);
        #pragma unroll
        for (int r = 0; r < 16; ++r) lm = fmaxf(lm, st1[r]);
        float full = fmaxf(lm, __shfl_xor(lm, 32));
        // ---- defer-max ----
        if (!__all(full <= m + 8.f)) {
            float mn = fmaxf(m, full);
            float sc = exp2fast(m - mn);
            m = mn;
            lsum *= sc;
            #pragma unroll
            for (int r = 0; r < 16; ++r) {
                int crow = (r & 3) + 8 * (r >> 2) + 4 * hi;
                float scr = __shfl(sc, crow);
                accA[r] *= scr;
                accB[r] *= scr;
            }
        }
        // ---- P = exp2(s - m), pack to bf16 pairs, accumulate row-sum ----
        unsigned int pk0[8], pk1[8];
        #pragma unroll
        for (int c = 0; c < 8; ++c) {
            float a0 = exp2fast(st0[2 * c] - m);
            float a1 = exp2fast(st0[2 * c + 1] - m);
            float b0 = exp2fast(st1[2 * c] - m);
            float b1 = exp2fast(st1[2 * c + 1] - m);
            lsum += (a0 + a1) + (b0 + b1);
            pk0[c] = pack2bf(a0, a1);
            pk1[c] = pack2bf(b0, b1);
        }
        // ---- PV: build PA per 16-k slot via cross-half exchange ----
        #pragma unroll
        for (int ks = 0; ks < 4; ++ks) {
            const int b4 = (ks & 1) * 4;
            unsigned int w0, w1, w2, w3;
            if (ks < 2) { w0 = pk0[b4]; w1 = pk0[b4 + 1]; w2 = pk0[b4 + 2]; w3 = pk0[b4 + 3]; }
            else        { w0 = pk1[b4]; w1 = pk1[b4 + 1]; w2 = pk1[b4 + 2]; w3 = pk1[b4 + 3]; }
            unsigned int x0 = __shfl_xor(hi ? w0 : w2, 32);
            unsigned int x1 = __shfl_xor(hi ? w1 : w3, 32);
            u32x4 uu;
            uu[0] = hi ? x0 : w0;
            uu[1] = hi ? x1 : w1;
            uu[2] = hi ? w2 : x0;
            uu[3] = hi ? w3 : x1;
            bf16x8 pa = __builtin_bit_cast(bf16x8, uu);
            bf16x8 bv0 = *reinterpret_cast<const bf16x8*>(&Vs[l31][ks * 16 + hi * 8]);
            bf16x8 bv1 = *reinterpret_cast<const bf16x8*>(&Vs[32 + l31][ks * 16 + hi * 8]);
            __builtin_amdgcn_s_setprio(1);
            accA = __builtin_amdgcn_mfma_f32_32x32x16_bf16(pa, bv0, accA, 0, 0, 0);
            accB = __builtin_amdgcn_mfma_f32_32x32x16_bf16(pa, bv1, accB, 0, 0, 0);
            __builtin_amdgcn_s_setprio(0);
        }
    }

    // ---- epilogue: combine halves' row-sum, write bf16 partials ----
    float lt = lsum + __shfl_xor(lsum, 32);
    const size_t pbbase = (((size_t)z * NHEAD + h) * 16 + qt) * 4096;
    const size_t pmbase = (((size_t)z * NHEAD + h) * 16 + qt) * 128;
    if (hi == 0) {
        int q = w * 32 + l31;
        pml[pmbase + q] = m;
        pml[pmbase + 64 + q] = lt;
    }
    #pragma unroll
    for (int r = 0; r < 16; ++r) {
        int crow = (r & 3) + 8 * (r >> 2) + 4 * hi;
        int q = w * 32 + crow;
        paccb[pbbase + q * 64 + l31] = f2bf(accA[r]);
        paccb[pbbase + q * 64 + 32 + l31] = f2bf(accB[r]);
    }
}

// ---------------------------------------------------------------------------
// merge NSPLIT bf16 split partials -> ctxb bf16 [1024 t][1024 (h*64+d)]
// ---------------------------------------------------------------------------
__global__ __launch_bounds__(256) void merge_ctx(
    const short* __restrict__ paccb, const float* __restrict__ pml,
    short* __restrict__ ctxb) {
    const int h = blockIdx.x, qt = blockIdx.y;
    const int t = threadIdx.x;
    const int q = t >> 2, ds = (t & 3) << 4;
    size_t bb[NSPLIT], bm[NSPLIT];
    float mz[NSPLIT], lz[NSPLIT];
    float M = -1e30f;
    #pragma unroll
    for (int z = 0; z < NSPLIT; ++z) {
        bb[z] = (((size_t)z * NHEAD + h) * 16 + qt) * 4096;
        bm[z] = (((size_t)z * NHEAD + h) * 16 + qt) * 128;
        mz[z] = pml[bm[z] + q];
        lz[z] = pml[bm[z] + 64 + q];
        M = fmaxf(M, mz[z]);
    }
    float L = 0.f, ez[NSPLIT];
    #pragma unroll
    for (int z = 0; z < NSPLIT; ++z) {
        ez[z] = __builtin_amdgcn_exp2f(mz[z] - M);
        L += lz[z] * ez[z];
    }
    float inv = 1.f / L;
    float v[16];
    #pragma unroll
    for (int j = 0; j < 16; ++j) v[j] = 0.f;
    #pragma unroll
    for (int z = 0; z < NSPLIT; ++z) {
        bf16x8 a0 = *reinterpret_cast<const bf16x8*>(&paccb[bb[z] + q * 64 + ds]);
        bf16x8 a1 = *reinterpret_cast<const bf16x8*>(&paccb[bb[z] + q * 64 + ds + 8]);
        #pragma unroll
        for (int j = 0; j < 8; ++j) {
            v[j]     += bf2f(a0[j]) * ez[z];
            v[8 + j] += bf2f(a1[j]) * ez[z];
        }
    }
    bf16x8 o0, o1;
    #pragma unroll
    for (int j = 0; j < 8; ++j) {
        o0[j] = f2bf(v[j] * inv);
        o1[j] = f2bf(v[8 + j] * inv);
    }
    size_t ob = (size_t)(qt * 64 + q) * NFEAT + h * DK + ds;
    *reinterpret_cast<bf16x8*>(&ctxb[ob]) = o0;
    *reinterpret_cast<bf16x8*>(&ctxb[ob + 8]) = o1;
}

extern "C" void kernel_launch(void* const* d_in, const int* in_sizes, int n_in,
                              void* d_out, int out_size, void* d_ws, size_t ws_size,
                              hipStream_t stream) {
    const float* x   = (const float*)d_in[0];
    const float* Wq  = (const float*)d_in[1];
    const float* bq  = (const float*)d_in[2];
    const float* Wk  = (const float*)d_in[3];
    const float* bk  = (const float*)d_in[4];
    const float* Wv  = (const float*)d_in[5];
    const float* bv  = (const float*)d_in[6];
    const float* Wo  = (const float*)d_in[7];
    const float* bo  = (const float*)d_in[8];
    const float* kc  = (const float*)d_in[9];
    const float* vc  = (const float*)d_in[10];
    const int*   bt  = (const int*)d_in[11];
    const int*   so  = (const int*)d_in[12];

    short* xb    = (short*)d_ws;                       // 1M bf16
    short* Wt    = xb + (size_t)1024 * 1024;           // 4M bf16
    short* qbuf  = Wt + (size_t)4096 * 1024;           // 1M bf16
    short* kg    = qbuf + (size_t)1024 * 1024;         // 4M bf16
    short* vtb   = kg + (size_t)NHEAD * MAXTOK * DK;   // 4M bf16
    short* paccb = vtb + (size_t)NHEAD * DK * MAXTOK;  // NSPLIT*256*4096 bf16
    float* pml   = (float*)(paccb + (size_t)NSPLIT * 256 * 4096);  // NSPLIT*256*128 f32
    short* ctxb  = (short*)(pml + (size_t)NSPLIT * 256 * 128);     // 1M bf16

    pack_kernel<<<dim3(1920), 256, 0, stream>>>(x, Wq, Wk, Wv, Wo, kc, vc, bt, so,
                                                xb, Wt, kg, vtb);
    qkv_gemm<<<dim3(24, 16), 256, 0, stream>>>(xb, Wt, bq, bk, bv, so,
                                               qbuf, kg, vtb);
    attn_mfma<<<dim3(16, 16, NSPLIT), 128, 0, stream>>>(qbuf, kg, vtb, so,
                                                        paccb, pml);
    merge_ctx<<<dim3(16, 16), 256, 0, stream>>>(paccb, pml, ctxb);
    out_gemm<<<dim3(16, 16), 256, 0, stream>>>(ctxb, Wt, bo, (float*)d_out);
}

// Round 20
// 97.781 us; speedup vs baseline: 1.2324x; 1.0016x over previous
//
#include <hip/hip_runtime.h>
#include <hip/hip_bf16.h>

#define NFEAT 1024
#define NHEAD 16
#define DK 64
#define TCHUNK 1024
#define MAXTOK 4096
#define NSPLIT 4

using bf16x8 = __attribute__((ext_vector_type(8))) short;
using f32x4  = __attribute__((ext_vector_type(4))) float;
using f32x16 = __attribute__((ext_vector_type(16))) float;
using u32x4  = __attribute__((ext_vector_type(4))) unsigned int;

__device__ __forceinline__ short f2bf(float f) {
    __hip_bfloat16 h = __float2bfloat16(f);
    return *reinterpret_cast<short*>(&h);
}

__device__ __forceinline__ float bf2f(short s) {
    unsigned int u = ((unsigned int)(unsigned short)s) << 16;
    return __builtin_bit_cast(float, u);
}

__device__ __forceinline__ float exp2fast(float x) {
    return __builtin_amdgcn_exp2f(x);
}

__device__ __forceinline__ unsigned int pack2bf(float a, float b) {
    unsigned int lo = (unsigned int)(unsigned short)f2bf(a);
    unsigned int hi = (unsigned int)(unsigned short)f2bf(b);
    return lo | (hi << 16);
}

// log2(e)/sqrt(DK): folds the 1/sqrt(64) and the exp->exp2 conversion
#define QSCALE 0.1803368801f

// ---------------------------------------------------------------------------
// pack: blocks [0,1024): transpose+convert W{q,k,v,o} -> Wt[4096 n][1024 k]
//       blocks [1024,1152): convert x -> xb bf16
//       blocks [1152,1920): gather cache tokens -> kg[h][tok][d], vt[h][d][tok]
// ---------------------------------------------------------------------------
__global__ __launch_bounds__(256) void pack_kernel(
    const float* __restrict__ x,
    const float* __restrict__ Wq, const float* __restrict__ Wk,
    const float* __restrict__ Wv, const float* __restrict__ Wo,
    const float* __restrict__ kc, const float* __restrict__ vc,
    const int* __restrict__ btab, const int* __restrict__ soff,
    short* __restrict__ xb, short* __restrict__ Wt,
    short* __restrict__ kg, short* __restrict__ vt) {
    const int b = blockIdx.x;
    const int t = threadIdx.x;
    if (b < 1024) {
        __shared__ short T[64][72];
        const int w = b >> 8, tile = b & 255;
        const int k0 = (tile >> 4) << 6, n0 = (tile & 15) << 6;
        const float* W = (w == 0) ? Wq : (w == 1) ? Wk : (w == 2) ? Wv : Wo;
        const int r = t >> 2, cs = (t & 3) << 4;
        #pragma unroll
        for (int u = 0; u < 4; ++u) {
            float4 v = *reinterpret_cast<const float4*>(
                &W[(size_t)(k0 + r) * NFEAT + n0 + cs + u * 4]);
            T[cs + u * 4 + 0][r] = f2bf(v.x);
            T[cs + u * 4 + 1][r] = f2bf(v.y);
            T[cs + u * 4 + 2][r] = f2bf(v.z);
            T[cs + u * 4 + 3][r] = f2bf(v.w);
        }
        __syncthreads();
        const int c = t >> 2, rs = (t & 3) << 4;
        bf16x8 a0 = *reinterpret_cast<const bf16x8*>(&T[c][rs]);
        bf16x8 a1 = *reinterpret_cast<const bf16x8*>(&T[c][rs + 8]);
        size_t drow = (size_t)(w * 1024 + n0 + c) * NFEAT + k0 + rs;
        *reinterpret_cast<bf16x8*>(&Wt[drow]) = a0;
        *reinterpret_cast<bf16x8*>(&Wt[drow + 8]) = a1;
    } else if (b < 1152) {
        const int e0 = ((b - 1024) * 256 + t) * 32;
        #pragma unroll
        for (int u = 0; u < 4; ++u) {
            float4 v0 = *reinterpret_cast<const float4*>(&x[e0 + u * 8]);
            float4 v1 = *reinterpret_cast<const float4*>(&x[e0 + u * 8 + 4]);
            bf16x8 o;
            o[0] = f2bf(v0.x); o[1] = f2bf(v0.y); o[2] = f2bf(v0.z); o[3] = f2bf(v0.w);
            o[4] = f2bf(v1.x); o[5] = f2bf(v1.y); o[6] = f2bf(v1.z); o[7] = f2bf(v1.w);
            *reinterpret_cast<bf16x8*>(&xb[e0 + u * 8]) = o;
        }
    } else {
        // cache-token gather (tokens [0, offset))
        __shared__ short TV[64][72];
        const int cb = b - 1152;
        const int h = cb & 15;
        const int t0 = (cb >> 4) << 6;
        const int offset = soff[0];
        const int row = t >> 2, ds = (t & 3) << 4;
        const int tok = t0 + row;
        short kv[16], vv[16];
        if (tok < offset) {
            int phys = btab[tok >> 5];
            size_t base = ((size_t)(phys * 32 + (tok & 31)) * NHEAD + h) * DK + ds;
            #pragma unroll
            for (int u = 0; u < 4; ++u) {
                float4 kf = *reinterpret_cast<const float4*>(&kc[base + u * 4]);
                float4 vf = *reinterpret_cast<const float4*>(&vc[base + u * 4]);
                kv[u * 4 + 0] = f2bf(kf.x); kv[u * 4 + 1] = f2bf(kf.y);
                kv[u * 4 + 2] = f2bf(kf.z); kv[u * 4 + 3] = f2bf(kf.w);
                vv[u * 4 + 0] = f2bf(vf.x); vv[u * 4 + 1] = f2bf(vf.y);
                vv[u * 4 + 2] = f2bf(vf.z); vv[u * 4 + 3] = f2bf(vf.w);
            }
        } else {
            #pragma unroll
            for (int e = 0; e < 16; ++e) { kv[e] = 0; vv[e] = 0; }
        }
        {
            bf16x8 a, bb;
            #pragma unroll
            for (int e = 0; e < 8; ++e) { a[e] = kv[e]; bb[e] = kv[8 + e]; }
            size_t kb = ((size_t)h * MAXTOK + tok) * DK + ds;
            *reinterpret_cast<bf16x8*>(&kg[kb]) = a;
            *reinterpret_cast<bf16x8*>(&kg[kb + 8]) = bb;
        }
        #pragma unroll
        for (int e = 0; e < 16; ++e) TV[ds + e][row] = vv[e];
        __syncthreads();
        {
            const int d = t >> 2, ts = (t & 3) << 4;
            bf16x8 a = *reinterpret_cast<const bf16x8*>(&TV[d][ts]);
            bf16x8 bb = *reinterpret_cast<const bf16x8*>(&TV[d][ts + 8]);
            size_t vb = ((size_t)h * DK + d) * MAXTOK + t0 + ts;
            *reinterpret_cast<bf16x8*>(&vt[vb]) = a;
            *reinterpret_cast<bf16x8*>(&vt[vb + 8]) = bb;
        }
    }
}

// ---------------------------------------------------------------------------
// QKV MFMA GEMM (64x128 tile, 384 blocks — best measured). sel==0 -> qbuf
// (scaled); sel==1 -> kg new-token region; sel==2 -> vt (transposed scatter).
// ---------------------------------------------------------------------------
__global__ __launch_bounds__(256) void qkv_gemm(
    const short* __restrict__ xb, const short* __restrict__ Wt,
    const float* __restrict__ bq, const float* __restrict__ bk,
    const float* __restrict__ bv, const int* __restrict__ soff,
    short* __restrict__ qbuf, short* __restrict__ kg, short* __restrict__ vt) {
    __shared__ short As[64][72];
    __shared__ short Bs[128][72];
    const int tid = threadIdx.x;
    const int lane = tid & 63;
    const int w = tid >> 6;
    const int l15 = lane & 15, lg = lane >> 4;
    const int wr = w >> 1, wc = w & 1;
    const int m0 = blockIdx.y << 6, n0 = blockIdx.x << 7;
    const int sel = n0 >> 10;
    const float* bias = (sel == 0) ? bq : (sel == 1) ? bk : bv;

    f32x4 acc[2][4];
    #pragma unroll
    for (int i = 0; i < 2; ++i)
        #pragma unroll
        for (int j = 0; j < 4; ++j) acc[i][j] = (f32x4){0.f, 0.f, 0.f, 0.f};

    for (int k0 = 0; k0 < NFEAT; k0 += 64) {
        #pragma unroll
        for (int r = 0; r < 2; ++r) {
            int f = tid + (r << 8);
            int row = f >> 3, kc = (f & 7) << 3;
            *reinterpret_cast<bf16x8*>(&As[row][kc]) =
                *reinterpret_cast<const bf16x8*>(&xb[(size_t)(m0 + row) * NFEAT + k0 + kc]);
        }
        #pragma unroll
        for (int r = 0; r < 4; ++r) {
            int f = tid + (r << 8);
            int row = f >> 3, kc = (f & 7) << 3;
            *reinterpret_cast<bf16x8*>(&Bs[row][kc]) =
                *reinterpret_cast<const bf16x8*>(&Wt[(size_t)(n0 + row) * NFEAT + k0 + kc]);
        }
        __syncthreads();
        #pragma unroll
        for (int kk = 0; kk < 2; ++kk) {
            bf16x8 am[2], bn[4];
            #pragma unroll
            for (int mi = 0; mi < 2; ++mi)
                am[mi] = *reinterpret_cast<const bf16x8*>(
                    &As[wr * 32 + mi * 16 + l15][kk * 32 + lg * 8]);
            #pragma unroll
            for (int ni = 0; ni < 4; ++ni)
                bn[ni] = *reinterpret_cast<const bf16x8*>(
                    &Bs[wc * 64 + ni * 16 + l15][kk * 32 + lg * 8]);
            #pragma unroll
            for (int mi = 0; mi < 2; ++mi)
                #pragma unroll
                for (int ni = 0; ni < 4; ++ni)
                    acc[mi][ni] = __builtin_amdgcn_mfma_f32_16x16x32_bf16(
                        am[mi], bn[ni], acc[mi][ni], 0, 0, 0);
        }
        __syncthreads();
    }
    const int offs = soff[0];
    #pragma unroll
    for (int mi = 0; mi < 2; ++mi)
        #pragma unroll
        for (int rr = 0; rr < 4; ++rr) {
            int m = m0 + wr * 32 + mi * 16 + lg * 4 + rr;
            #pragma unroll
            for (int ni = 0; ni < 4; ++ni) {
                int n = n0 + wc * 64 + ni * 16 + l15;
                float v = acc[mi][ni][rr] + bias[n & 1023];
                if (sel == 0) {
                    qbuf[(size_t)m * NFEAT + n] = f2bf(v * QSCALE);
                } else if (sel == 1) {
                    int nn = n - 1024, hh = nn >> 6, dd = nn & 63;
                    kg[((size_t)hh * MAXTOK + offs + m) * DK + dd] = f2bf(v);
                } else {
                    int nn = n - 2048, hh = nn >> 6, dd = nn & 63;
                    vt[((size_t)hh * DK + dd) * MAXTOK + offs + m] = f2bf(v);
                }
            }
        }
}

// ---------------------------------------------------------------------------
// Output MFMA GEMM: out[1024][1024] f32 = ctxb @ Wo + bo.
// ---------------------------------------------------------------------------
__global__ __launch_bounds__(256) void out_gemm(
    const short* __restrict__ ctxb, const short* __restrict__ Wt,
    const float* __restrict__ bo, float* __restrict__ out) {
    __shared__ short As[64][72];
    __shared__ short Bs[64][72];
    const int tid = threadIdx.x;
    const int lane = tid & 63;
    const int w = tid >> 6;
    const int l15 = lane & 15, lg = lane >> 4;
    const int wr = w >> 1, wc = w & 1;
    const int m0 = blockIdx.y << 6, n0 = blockIdx.x << 6;

    f32x4 acc[2][2];
    #pragma unroll
    for (int i = 0; i < 2; ++i)
        #pragma unroll
        for (int j = 0; j < 2; ++j) acc[i][j] = (f32x4){0.f, 0.f, 0.f, 0.f};

    for (int k0 = 0; k0 < NFEAT; k0 += 64) {
        #pragma unroll
        for (int r = 0; r < 2; ++r) {
            int f = tid + (r << 8);
            int row = f >> 3, kc = (f & 7) << 3;
            *reinterpret_cast<bf16x8*>(&As[row][kc]) =
                *reinterpret_cast<const bf16x8*>(&ctxb[(size_t)(m0 + row) * NFEAT + k0 + kc]);
            *reinterpret_cast<bf16x8*>(&Bs[row][kc]) =
                *reinterpret_cast<const bf16x8*>(
                    &Wt[(size_t)(3072 + n0 + row) * NFEAT + k0 + kc]);
        }
        __syncthreads();
        #pragma unroll
        for (int kk = 0; kk < 2; ++kk) {
            bf16x8 am[2], bn[2];
            #pragma unroll
            for (int mi = 0; mi < 2; ++mi)
                am[mi] = *reinterpret_cast<const bf16x8*>(
                    &As[wr * 32 + mi * 16 + l15][kk * 32 + lg * 8]);
            #pragma unroll
            for (int ni = 0; ni < 2; ++ni)
                bn[ni] = *reinterpret_cast<const bf16x8*>(
                    &Bs[wc * 32 + ni * 16 + l15][kk * 32 + lg * 8]);
            #pragma unroll
            for (int mi = 0; mi < 2; ++mi)
                #pragma unroll
                for (int ni = 0; ni < 2; ++ni)
                    acc[mi][ni] = __builtin_amdgcn_mfma_f32_16x16x32_bf16(
                        am[mi], bn[ni], acc[mi][ni], 0, 0, 0);
        }
        __syncthreads();
    }
    #pragma unroll
    for (int mi = 0; mi < 2; ++mi)
        #pragma unroll
        for (int rr = 0; rr < 4; ++rr) {
            int m = m0 + wr * 32 + mi * 16 + lg * 4 + rr;
            #pragma unroll
            for (int ni = 0; ni < 2; ++ni) {
                int n = n0 + wc * 32 + ni * 16 + l15;
                out[(size_t)m * NFEAT + n] = acc[mi][ni][rr] + bo[n];
            }
        }
}

// ---------------------------------------------------------------------------
// MFMA flash attention v19 — swapped-operand 32x32, P fully in-register,
// bf16 split partials. Grid (16 h, 16 qt, 4 z), block 128 (2 waves).
// ---------------------------------------------------------------------------
__global__ __launch_bounds__(128, 2) void attn_mfma(
    const short* __restrict__ qbuf, const short* __restrict__ kg,
    const short* __restrict__ vt, const int* __restrict__ soff,
    short* __restrict__ paccb, float* __restrict__ pml) {
    __shared__ short Ks[64][72];
    __shared__ short Vs[64][72];   // [d][tok]

    const int tid = threadIdx.x;
    const int lane = tid & 63;
    const int w = tid >> 6;        // 0/1
    const int l31 = lane & 31;
    const int hi = lane >> 5;
    const int h = blockIdx.x;
    const int qt = blockIdx.y;
    const int z = blockIdx.z;
    const int offset = soff[0];
    const int total = offset + TCHUNK;
    const int ntiles = (total + 63) >> 6;
    const int NT = (ntiles + NSPLIT - 1) / NSPLIT;
    const int tbase = z * NT;
    const int tend = min(tbase + NT, ntiles);

    const int srow = tid >> 1;           // 0..63 (tok for K, d for V)
    const int sseg = (tid & 1) << 5;     // 0 or 32

    const short* kbase = kg + (size_t)h * MAXTOK * DK;
    const short* vbase = vt + (size_t)h * DK * MAXTOK;

    // Q B-fragments: q = qt*64 + w*32 + l31, d = 16j + 8hi + e
    bf16x8 qf[4];
    {
        size_t qrow = (size_t)(qt * 64 + w * 32 + l31) * NFEAT + h * DK;
        #pragma unroll
        for (int j = 0; j < 4; ++j)
            qf[j] = *reinterpret_cast<const bf16x8*>(&qbuf[qrow + j * 16 + hi * 8]);
    }

    float m = -1e30f, lsum = 0.f;
    f32x16 accA, accB;
    #pragma unroll
    for (int i = 0; i < 16; ++i) { accA[i] = 0.f; accB[i] = 0.f; }

    bf16x8 kr[4], vr[4];
    if (tbase < tend) {
        int tok0 = tbase << 6;
        #pragma unroll
        for (int j = 0; j < 4; ++j) {
            kr[j] = *reinterpret_cast<const bf16x8*>(
                &kbase[(size_t)(tok0 + srow) * DK + sseg + j * 8]);
            vr[j] = *reinterpret_cast<const bf16x8*>(
                &vbase[(size_t)srow * MAXTOK + tok0 + sseg + j * 8]);
        }
    }

    for (int t = tbase; t < tend; ++t) {
        __syncthreads();   // previous tile fully consumed
        #pragma unroll
        for (int j = 0; j < 4; ++j) {
            *reinterpret_cast<bf16x8*>(&Ks[srow][sseg + j * 8]) = kr[j];
            *reinterpret_cast<bf16x8*>(&Vs[srow][sseg + j * 8]) = vr[j];
        }
        __syncthreads();   // staged tile visible
        if (t + 1 < tend) {   // prefetch next tile into regs
            int tok0 = (t + 1) << 6;
            #pragma unroll
            for (int j = 0; j < 4; ++j) {
                kr[j] = *reinterpret_cast<const bf16x8*>(
                    &kbase[(size_t)(tok0 + srow) * DK + sseg + j * 8]);
                vr[j] = *reinterpret_cast<const bf16x8*>(
                    &vbase[(size_t)srow * MAXTOK + tok0 + sseg + j * 8]);
            }
        }

        const int kt0 = t << 6;
        // ---- S^T = K * Q^T (two tok-halves, 4 d-steps) ----
        f32x16 st0, st1;
        #pragma unroll
        for (int i = 0; i < 16; ++i) { st0[i] = 0.f; st1[i] = 0.f; }
        __builtin_amdgcn_s_setprio(1);
        #pragma unroll
        for (int j = 0; j < 4; ++j) {
            bf16x8 ka0 = *reinterpret_cast<const bf16x8*>(&Ks[l31][j * 16 + hi * 8]);
            bf16x8 ka1 = *reinterpret_cast<const bf16x8*>(&Ks[32 + l31][j * 16 + hi * 8]);
            st0 = __builtin_amdgcn_mfma_f32_32x32x16_bf16(ka0, qf[j], st0, 0, 0, 0);
            st1 = __builtin_amdgcn_mfma_f32_32x32x16_bf16(ka1, qf[j], st1, 0, 0, 0);
        }
        __builtin_amdgcn_s_setprio(0);
        // ---- mask (uniform last-tile branch) ----
        if (kt0 + 64 > total) {
            #pragma unroll
            for (int r = 0; r < 16; ++r) {
                int crow = (r & 3) + 8 * (r >> 2) + 4 * hi;
                if (kt0 + crow >= total) st0[r] = -1e30f;
                if (kt0 + 32 + crow >= total) st1[r] = -1e30f;
            }
        }
        // ---- in-lane row max + cross-half ----
        float lm = st0[0];
        #pragma unroll
        for (int r = 1; r < 16; ++r) lm = fmaxf(lm, st0[r]);
        #pragma unroll
        for (int r = 0; r < 16; ++r) lm = fmaxf(lm, st1[r]);
        float full = fmaxf(lm, __shfl_xor(lm, 32));
        // ---- defer-max ----
        if (!__all(full <= m + 8.f)) {
            float mn = fmaxf(m, full);
            float sc = exp2fast(m - mn);
            m = mn;
            lsum *= sc;
            #pragma unroll
            for (int r = 0; r < 16; ++r) {
                int crow = (r & 3) + 8 * (r >> 2) + 4 * hi;
                float scr = __shfl(sc, crow);
                accA[r] *= scr;
                accB[r] *= scr;
            }
        }
        // ---- P = exp2(s - m), pack to bf16 pairs, accumulate row-sum ----
        unsigned int pk0[8], pk1[8];
        #pragma unroll
        for (int c = 0; c < 8; ++c) {
            float a0 = exp2fast(st0[2 * c] - m);
            float a1 = exp2fast(st0[2 * c + 1] - m);
            float b0 = exp2fast(st1[2 * c] - m);
            float b1 = exp2fast(st1[2 * c + 1] - m);
            lsum += (a0 + a1) + (b0 + b1);
            pk0[c] = pack2bf(a0, a1);
            pk1[c] = pack2bf(b0, b1);
        }
        // ---- PV: build PA per 16-k slot via cross-half exchange ----
        #pragma unroll
        for (int ks = 0; ks < 4; ++ks) {
            const int b4 = (ks & 1) * 4;
            unsigned int w0, w1, w2, w3;
            if (ks < 2) { w0 = pk0[b4]; w1 = pk0[b4 + 1]; w2 = pk0[b4 + 2]; w3 = pk0[b4 + 3]; }
            else        { w0 = pk1[b4]; w1 = pk1[b4 + 1]; w2 = pk1[b4 + 2]; w3 = pk1[b4 + 3]; }
            unsigned int x0 = __shfl_xor(hi ? w0 : w2, 32);
            unsigned int x1 = __shfl_xor(hi ? w1 : w3, 32);
            u32x4 uu;
            uu[0] = hi ? x0 : w0;
            uu[1] = hi ? x1 : w1;
            uu[2] = hi ? w2 : x0;
            uu[3] = hi ? w3 : x1;
            bf16x8 pa = __builtin_bit_cast(bf16x8, uu);
            bf16x8 bv0 = *reinterpret_cast<const bf16x8*>(&Vs[l31][ks * 16 + hi * 8]);
            bf16x8 bv1 = *reinterpret_cast<const bf16x8*>(&Vs[32 + l31][ks * 16 + hi * 8]);
            __builtin_amdgcn_s_setprio(1);
            accA = __builtin_amdgcn_mfma_f32_32x32x16_bf16(pa, bv0, accA, 0, 0, 0);
            accB = __builtin_amdgcn_mfma_f32_32x32x16_bf16(pa, bv1, accB, 0, 0, 0);
            __builtin_amdgcn_s_setprio(0);
        }
    }

    // ---- epilogue: combine halves' row-sum, write bf16 partials ----
    float lt = lsum + __shfl_xor(lsum, 32);
    const size_t pbbase = (((size_t)z * NHEAD + h) * 16 + qt) * 4096;
    const size_t pmbase = (((size_t)z * NHEAD + h) * 16 + qt) * 128;
    if (hi == 0) {
        int q = w * 32 + l31;
        pml[pmbase + q] = m;
        pml[pmbase + 64 + q] = lt;
    }
    #pragma unroll
    for (int r = 0; r < 16; ++r) {
        int crow = (r & 3) + 8 * (r >> 2) + 4 * hi;
        int q = w * 32 + crow;
        paccb[pbbase + q * 64 + l31] = f2bf(accA[r]);
        paccb[pbbase + q * 64 + 32 + l31] = f2bf(accB[r]);
    }
}

// ---------------------------------------------------------------------------
// merge NSPLIT bf16 split partials -> ctxb bf16 [1024 t][1024 (h*64+d)]
// ---------------------------------------------------------------------------
__global__ __launch_bounds__(256) void merge_ctx(
    const short* __restrict__ paccb, const float* __restrict__ pml,
    short* __restrict__ ctxb) {
    const int h = blockIdx.x, qt = blockIdx.y;
    const int t = threadIdx.x;
    const int q = t >> 2, ds = (t & 3) << 4;
    size_t bb[NSPLIT], bm[NSPLIT];
    float mz[NSPLIT], lz[NSPLIT];
    float M = -1e30f;
    #pragma unroll
    for (int z = 0; z < NSPLIT; ++z) {
        bb[z] = (((size_t)z * NHEAD + h) * 16 + qt) * 4096;
        bm[z] = (((size_t)z * NHEAD + h) * 16 + qt) * 128;
        mz[z] = pml[bm[z] + q];
        lz[z] = pml[bm[z] + 64 + q];
        M = fmaxf(M, mz[z]);
    }
    float L = 0.f, ez[NSPLIT];
    #pragma unroll
    for (int z = 0; z < NSPLIT; ++z) {
        ez[z] = __builtin_amdgcn_exp2f(mz[z] - M);
        L += lz[z] * ez[z];
    }
    float inv = 1.f / L;
    float v[16];
    #pragma unroll
    for (int j = 0; j < 16; ++j) v[j] = 0.f;
    #pragma unroll
    for (int z = 0; z < NSPLIT; ++z) {
        bf16x8 a0 = *reinterpret_cast<const bf16x8*>(&paccb[bb[z] + q * 64 + ds]);
        bf16x8 a1 = *reinterpret_cast<const bf16x8*>(&paccb[bb[z] + q * 64 + ds + 8]);
        #pragma unroll
        for (int j = 0; j < 8; ++j) {
            v[j]     += bf2f(a0[j]) * ez[z];
            v[8 + j] += bf2f(a1[j]) * ez[z];
        }
    }
    bf16x8 o0, o1;
    #pragma unroll
    for (int j = 0; j < 8; ++j) {
        o0[j] = f2bf(v[j] * inv);
        o1[j] = f2bf(v[8 + j] * inv);
    }
    size_t ob = (size_t)(qt * 64 + q) * NFEAT + h * DK + ds;
    *reinterpret_cast<bf16x8*>(&ctxb[ob]) = o0;
    *reinterpret_cast<bf16x8*>(&ctxb[ob + 8]) = o1;
}

extern "C" void kernel_launch(void* const* d_in, const int* in_sizes, int n_in,
                              void* d_out, int out_size, void* d_ws, size_t ws_size,
                              hipStream_t stream) {
    const float* x   = (const float*)d_in[0];
    const float* Wq  = (const float*)d_in[1];
    const float* bq  = (const float*)d_in[2];
    const float* Wk  = (const float*)d_in[3];
    const float* bk  = (const float*)d_in[4];
    const float* Wv  = (const float*)d_in[5];
    const float* bv  = (const float*)d_in[6];
    const float* Wo  = (const float*)d_in[7];
    const float* bo  = (const float*)d_in[8];
    const float* kc  = (const float*)d_in[9];
    const float* vc  = (const float*)d_in[10];
    const int*   bt  = (const int*)d_in[11];
    const int*   so  = (const int*)d_in[12];

    short* xb    = (short*)d_ws;                       // 1M bf16
    short* Wt    = xb + (size_t)1024 * 1024;           // 4M bf16
    short* qbuf  = Wt + (size_t)4096 * 1024;           // 1M bf16
    short* kg    = qbuf + (size_t)1024 * 1024;         // 4M bf16
    short* vtb   = kg + (size_t)NHEAD * MAXTOK * DK;   // 4M bf16
    short* paccb = vtb + (size_t)NHEAD * DK * MAXTOK;  // NSPLIT*256*4096 bf16
    float* pml   = (float*)(paccb + (size_t)NSPLIT * 256 * 4096);  // NSPLIT*256*128 f32
    short* ctxb  = (short*)(pml + (size_t)NSPLIT * 256 * 128);     // 1M bf16

    pack_kernel<<<dim3(1920), 256, 0, stream>>>(x, Wq, Wk, Wv, Wo, kc, vc, bt, so,
                                                xb, Wt, kg, vtb);
    qkv_gemm<<<dim3(24, 16), 256, 0, stream>>>(xb, Wt, bq, bk, bv, so,
                                               qbuf, kg, vtb);
    attn_mfma<<<dim3(16, 16, NSPLIT), 128, 0, stream>>>(qbuf, kg, vtb, so,
                                                        paccb, pml);
    merge_ctx<<<dim3(16, 16), 256, 0, stream>>>(paccb, pml, ctxb);
    out_gemm<<<dim3(16, 16), 256, 0, stream>>>(ctxb, Wt, bo, (float*)d_out);
}